// Round 3
// baseline (19470.453 us; speedup 1.0000x reference)
//
#include <hip/hip_runtime.h>

#define H_ 1024
#define B_ 128
#define S_ 512
#define V_ 128
#define E_ 256

#define BK_ROW 264              // bf16 elems per kk-row: 32 cols * 8 + 8 pad (528 B, 16B-aligned)
#define ZSH_ROW 36              // 32 + 4 pad (f32)
#define TSH_ROW 33              // 32 + 1 pad (f32)
#define BSH_BYTES (128 * BK_ROW * 2)        // 67584
#define ZSH_BYTES (2 * 128 * ZSH_ROW * 4)   // 36864 (two k-group partials)
#define TSH_BYTES (128 * TSH_ROW * 4)       // 16896
#define SMEM_TOTAL (BSH_BYTES + ZSH_BYTES + TSH_BYTES + 512)  // 121856

typedef __bf16 bf16x8 __attribute__((ext_vector_type(8)));
typedef float f32x4 __attribute__((ext_vector_type(4)));

__device__ __forceinline__ unsigned short f2bf(float f) {
  unsigned u = __float_as_uint(f);
  u += 0x7fffu + ((u >> 16) & 1u);   // round-to-nearest-even
  return (unsigned short)(u >> 16);
}
__device__ __forceinline__ float sigf(float x) { return 1.0f / (1.0f + __expf(-x)); }
__device__ __forceinline__ float tanhfast(float x) { return 1.0f - 2.0f / (1.0f + __expf(2.0f * x)); }

// ---- device-scope grid barrier (monotonic counter, no reset) ----
__device__ __forceinline__ void gbar(unsigned* cnt, unsigned target) {
  __threadfence();      // release own stores at agent scope
  __syncthreads();
  if (threadIdx.x == 0) {
    __hip_atomic_fetch_add(cnt, 1u, __ATOMIC_RELEASE, __HIP_MEMORY_SCOPE_AGENT);
    while (__hip_atomic_load(cnt, __ATOMIC_RELAXED, __HIP_MEMORY_SCOPE_AGENT) < target) {
      __builtin_amdgcn_s_sleep(1);
    }
    __threadfence();    // acquire: invalidate stale L1/L2 before reading others' h
  }
  __syncthreads();
}

// ---- tokproj[v][n*32 + gate*8 + hu] = emb[v]@Wx + b  (block-local layout) ----
__global__ void __launch_bounds__(256)
tokproj_kernel(const float* __restrict__ emb,
               const float* __restrict__ Wgx, const float* __restrict__ Wix,
               const float* __restrict__ Wfx, const float* __restrict__ Wox,
               const float* __restrict__ bg, const float* __restrict__ bi,
               const float* __restrict__ bf_, const float* __restrict__ bo,
               float* __restrict__ tokproj) {
  __shared__ float esh[E_];
  const int v = blockIdx.x;
  const int c = blockIdx.y * 256 + threadIdx.x;
  const int gate = c >> 10;
  const int j = c & 1023;
  const float* W = (gate == 0) ? Wgx : (gate == 1) ? Wix : (gate == 2) ? Wfx : Wox;
  const float* bias = (gate == 0) ? bg : (gate == 1) ? bi : (gate == 2) ? bf_ : bo;
  esh[threadIdx.x] = emb[v * E_ + threadIdx.x];
  __syncthreads();
  float acc = bias[j];
#pragma unroll 4
  for (int e = 0; e < E_; ++e) acc += esh[e] * W[e * H_ + j];
  tokproj[v * 4096 + (j >> 3) * 32 + gate * 8 + (j & 7)] = acc;
}

// ---- WhT[c][k] = bf16(Wh_gate[k][j]) ; c = gate*1024 + j ----
__global__ void __launch_bounds__(256)
wht_kernel(const float* __restrict__ Wgh, const float* __restrict__ Wih,
           const float* __restrict__ Wfh, const float* __restrict__ Woh,
           unsigned short* __restrict__ WhT) {
  const int c = blockIdx.x;
  const int gate = c >> 10;
  const int j = c & 1023;
  const float* W = (gate == 0) ? Wgh : (gate == 1) ? Wih : (gate == 2) ? Wfh : Woh;
  for (int k = threadIdx.x; k < H_; k += 256)
    WhT[c * H_ + k] = f2bf(W[k * H_ + j]);
}

// ---- xT[s][b] = x[b][s] ----
__global__ void __launch_bounds__(256)
xpose_kernel(const int* __restrict__ x, int* __restrict__ xT) {
  const int id = blockIdx.x * 256 + threadIdx.x;  // 65536
  const int s = id >> 7, b = id & 127;
  xT[s * 128 + b] = x[b * S_ + s];
}

// ---- persistent scan: 128 blocks x 512 thr; block n owns hidden [n*8, n*8+8) ----
// waves 0-3: k in [0,512); waves 4-7: k in [512,1024). Partial Z summed in gate pass.
__global__ void __launch_bounds__(512, 2)
lstm_scan(const int* __restrict__ xT, const float* __restrict__ tokproj,
          const unsigned short* __restrict__ WhT,
          unsigned short* __restrict__ hbuf, float* __restrict__ hfin,
          unsigned* __restrict__ cnt) {
  extern __shared__ char smem[];
  unsigned short* Bsh = (unsigned short*)smem;                       // [128 kk][264]
  float* Zsh = (float*)(smem + BSH_BYTES);                           // [2][128][36]
  float* tsh = (float*)(smem + BSH_BYTES + ZSH_BYTES);               // [128][33]
  int* xsh = (int*)(smem + BSH_BYTES + ZSH_BYTES + TSH_BYTES);       // [128]

  const int n = blockIdx.x;
  const int tid = threadIdx.x;
  const int w = tid >> 6;
  const int g = w >> 2;           // k-group (0/1)
  const int wm = w & 3;           // m-group
  const int lane = tid & 63;
  const int l15 = lane & 15;
  const int lq = lane >> 4;

  // ---- one-time LDS fills ----
  // B slice: Bsh[kk*BK_ROW + j*8 + e] = WhT[c(j)*1024 + kk*8 + e]
  for (int it = tid; it < 4096; it += 512) {
    const int j = it >> 7, kk = it & 127;
    const int c = ((j >> 3) << 10) + n * 8 + (j & 7);
    *(uint4*)(Bsh + kk * BK_ROW + j * 8) = *(const uint4*)(WhT + c * 1024 + kk * 8);
  }
  // tokproj slice
  for (int it = tid; it < 4096; it += 512) {
    const int v = it >> 5, off = it & 31;
    tsh[v * TSH_ROW + off] = tokproj[v * 4096 + n * 32 + off];
  }

  const int b_own = tid >> 2;        // batch row this thread owns in gate pass
  const int hu0 = (tid & 3) << 1;    // first of 2 hidden units
  const int col0 = n * 8 + hu0;      // global h column

  float creg[2] = {0.f, 0.f};
  *(unsigned*)(hbuf + b_own * H_ + col0) = 0u;  // zero h^{-1} (buf 0)

  unsigned phase = 1;
  gbar(cnt, phase * 128u);

  const int arow = wm * 32 + l15;
  const unsigned short* bbase = Bsh + (g * 64 + lq) * BK_ROW + l15 * 8;
  float* zb = Zsh + g * (128 * ZSH_ROW);

  for (int s = 0; s < S_; ++s) {
    const unsigned short* rd = hbuf + (s & 1) * (B_ * H_);
    unsigned short* wr = hbuf + ((s + 1) & 1) * (B_ * H_);

    if (tid < 128) xsh[tid] = xT[s * 128 + tid];

    const unsigned short* a0p = rd + arow * H_ + g * 512 + lq * 8;
    const unsigned short* a1p = a0p + 16 * H_;

    // issue ALL A-fragment loads up front (full MLP against post-invalidate latency)
    uint4 ab[8][4];
#pragma unroll
    for (int kt = 0; kt < 8; ++kt) {
      ab[kt][0] = *(const uint4*)(a0p + kt * 64);
      ab[kt][1] = *(const uint4*)(a0p + kt * 64 + 32);
      ab[kt][2] = *(const uint4*)(a1p + kt * 64);
      ab[kt][3] = *(const uint4*)(a1p + kt * 64 + 32);
    }

    f32x4 acc00 = {0.f, 0.f, 0.f, 0.f}, acc01 = {0.f, 0.f, 0.f, 0.f};
    f32x4 acc10 = {0.f, 0.f, 0.f, 0.f}, acc11 = {0.f, 0.f, 0.f, 0.f};

#pragma unroll
    for (int kt = 0; kt < 8; ++kt) {
      bf16x8 b00 = *(const bf16x8*)(bbase + (kt * 8) * BK_ROW);
      bf16x8 b01 = *(const bf16x8*)(bbase + (kt * 8) * BK_ROW + 128);
      bf16x8 b10 = *(const bf16x8*)(bbase + (kt * 8 + 4) * BK_ROW);
      bf16x8 b11 = *(const bf16x8*)(bbase + (kt * 8 + 4) * BK_ROW + 128);
      bf16x8 a00 = __builtin_bit_cast(bf16x8, ab[kt][0]);
      bf16x8 a01 = __builtin_bit_cast(bf16x8, ab[kt][1]);
      bf16x8 a10 = __builtin_bit_cast(bf16x8, ab[kt][2]);
      bf16x8 a11 = __builtin_bit_cast(bf16x8, ab[kt][3]);
      acc00 = __builtin_amdgcn_mfma_f32_16x16x32_bf16(a00, b00, acc00, 0, 0, 0);
      acc01 = __builtin_amdgcn_mfma_f32_16x16x32_bf16(a00, b01, acc01, 0, 0, 0);
      acc10 = __builtin_amdgcn_mfma_f32_16x16x32_bf16(a10, b00, acc10, 0, 0, 0);
      acc11 = __builtin_amdgcn_mfma_f32_16x16x32_bf16(a10, b01, acc11, 0, 0, 0);
      acc00 = __builtin_amdgcn_mfma_f32_16x16x32_bf16(a01, b10, acc00, 0, 0, 0);
      acc01 = __builtin_amdgcn_mfma_f32_16x16x32_bf16(a01, b11, acc01, 0, 0, 0);
      acc10 = __builtin_amdgcn_mfma_f32_16x16x32_bf16(a11, b10, acc10, 0, 0, 0);
      acc11 = __builtin_amdgcn_mfma_f32_16x16x32_bf16(a11, b11, acc11, 0, 0, 0);
    }

    // C/D layout: col = lane&15, row = (lane>>4)*4 + reg
#pragma unroll
    for (int r = 0; r < 4; ++r) {
      const int m0 = wm * 32 + lq * 4 + r;
      zb[m0 * ZSH_ROW + l15] = acc00[r];
      zb[m0 * ZSH_ROW + 16 + l15] = acc01[r];
      zb[(m0 + 16) * ZSH_ROW + l15] = acc10[r];
      zb[(m0 + 16) * ZSH_ROW + 16 + l15] = acc11[r];
    }
    __syncthreads();

    // gate pass: thread owns (b_own, hu0..hu0+1); z = partial0 + partial1
    {
      const int xb = xsh[b_own];
      const float* z0 = Zsh + b_own * ZSH_ROW;
      const float* z1 = z0 + 128 * ZSH_ROW;
      const float* tp = tsh + xb * TSH_ROW;
      float hv[2];
#pragma unroll
      for (int q = 0; q < 2; ++q) {
        const int i0 = hu0 + q;
        float gv = tanhfast(z0[i0] + z1[i0] + tp[i0]);
        float iv = sigf(z0[8 + i0] + z1[8 + i0] + tp[8 + i0]);
        float fv = sigf(z0[16 + i0] + z1[16 + i0] + tp[16 + i0]);
        float ov = sigf(z0[24 + i0] + z1[24 + i0] + tp[24 + i0]);
        creg[q] = gv * iv + creg[q] * fv;
        hv[q] = tanhfast(creg[q]) * ov;
      }
      *(unsigned*)(wr + b_own * H_ + col0) =
          (unsigned)f2bf(hv[0]) | ((unsigned)f2bf(hv[1]) << 16);
      if (s == S_ - 1) {
        float2 h2; h2.x = hv[0]; h2.y = hv[1];
        *(float2*)(hfin + b_own * H_ + col0) = h2;
      }
    }
    ++phase;
    gbar(cnt, phase * 128u);
  }
}

// ---- p = hfin @ W_ph + b_p ; out = log_softmax(p) ----
__global__ void __launch_bounds__(256)
classify_kernel(const float* __restrict__ hfin, const float* __restrict__ Wph,
                const float* __restrict__ bp, float* __restrict__ out) {
  __shared__ float red[256 * 10];
  const int b = blockIdx.x, tid = threadIdx.x;
  float acc[10];
#pragma unroll
  for (int c = 0; c < 10; ++c) acc[c] = 0.f;
  for (int k = tid; k < H_; k += 256) {
    const float hv = hfin[b * H_ + k];
    const float* w = Wph + k * 10;
#pragma unroll
    for (int c = 0; c < 10; ++c) acc[c] += hv * w[c];
  }
#pragma unroll
  for (int c = 0; c < 10; ++c) red[tid * 10 + c] = acc[c];
  __syncthreads();
  for (int off = 128; off >= 1; off >>= 1) {
    if (tid < off) {
#pragma unroll
      for (int c = 0; c < 10; ++c) red[tid * 10 + c] += red[(tid + off) * 10 + c];
    }
    __syncthreads();
  }
  if (tid == 0) {
    float p[10];
    float m = -1e30f;
#pragma unroll
    for (int c = 0; c < 10; ++c) { p[c] = red[c] + bp[c]; m = fmaxf(m, p[c]); }
    float ssum = 0.f;
#pragma unroll
    for (int c = 0; c < 10; ++c) ssum += __expf(p[c] - m);
    const float lse = m + __logf(ssum);
#pragma unroll
    for (int c = 0; c < 10; ++c) out[b * 10 + c] = p[c] - lse;
  }
}

extern "C" void kernel_launch(void* const* d_in, const int* in_sizes, int n_in,
                              void* d_out, int out_size, void* d_ws, size_t ws_size,
                              hipStream_t stream) {
  (void)in_sizes; (void)n_in; (void)out_size; (void)ws_size;
  const int* x = (const int*)d_in[0];
  const float* emb = (const float*)d_in[1];
  const float* Wgx = (const float*)d_in[2];
  const float* Wgh = (const float*)d_in[3];
  const float* bg = (const float*)d_in[4];
  const float* Wix = (const float*)d_in[5];
  const float* Wih = (const float*)d_in[6];
  const float* bi = (const float*)d_in[7];
  const float* Wfx = (const float*)d_in[8];
  const float* Wfh = (const float*)d_in[9];
  const float* bf_ = (const float*)d_in[10];
  const float* Wox = (const float*)d_in[11];
  const float* Woh = (const float*)d_in[12];
  const float* bo = (const float*)d_in[13];
  const float* Wph = (const float*)d_in[14];
  const float* bp = (const float*)d_in[15];
  float* out = (float*)d_out;

  char* ws = (char*)d_ws;
  float* tokproj = (float*)ws;                                  // 2 MB
  unsigned short* WhT = (unsigned short*)(ws + 2097152);        // 8 MB
  unsigned short* hbuf = (unsigned short*)(ws + 10485760);      // 512 KB (2 bufs)
  float* hfin = (float*)(ws + 11010048);                        // 512 KB
  unsigned* cnt = (unsigned*)(ws + 11534336);                   // 4 B (+pad)
  int* xT = (int*)(ws + 11538432);                              // 256 KB

  hipMemsetAsync(cnt, 0, 4, stream);
  hipFuncSetAttribute(reinterpret_cast<const void*>(lstm_scan),
                      hipFuncAttributeMaxDynamicSharedMemorySize, SMEM_TOTAL);

  tokproj_kernel<<<dim3(V_, 16), dim3(256), 0, stream>>>(
      emb, Wgx, Wix, Wfx, Wox, bg, bi, bf_, bo, tokproj);
  wht_kernel<<<dim3(4096), dim3(256), 0, stream>>>(Wgh, Wih, Wfh, Woh, WhT);
  xpose_kernel<<<dim3(256), dim3(256), 0, stream>>>(x, xT);
  lstm_scan<<<dim3(128), dim3(512), SMEM_TOTAL, stream>>>(
      xT, tokproj, WhT, hbuf, hfin, cnt);
  classify_kernel<<<dim3(128), dim3(256), 0, stream>>>(hfin, Wph, bp, out);
}

// Round 4
// 9326.431 us; speedup vs baseline: 2.0877x; 2.0877x over previous
//
#include <hip/hip_runtime.h>

#define H_ 1024
#define B_ 128
#define S_ 512
#define V_ 128
#define E_ 256

#define BK_ROW 264              // bf16 elems per kk-row: 32 cols * 8 + 8 pad
#define ZSH_ROW 36              // 32 + 4 pad (f32)
#define TSH_ROW 33              // 32 + 1 pad (f32)
#define BSH_BYTES (128 * BK_ROW * 2)        // 67584
#define ZSH_BYTES (2 * 128 * ZSH_ROW * 4)   // 36864 (two k-group partials)
#define TSH_BYTES (128 * TSH_ROW * 4)       // 16896
#define SMEM_TOTAL (BSH_BYTES + ZSH_BYTES + TSH_BYTES + 512)  // 121856

typedef __bf16 bf16x8 __attribute__((ext_vector_type(8)));
typedef float f32x4 __attribute__((ext_vector_type(4)));

#define ALD(p) __hip_atomic_load((const unsigned long long*)(p), __ATOMIC_RELAXED, __HIP_MEMORY_SCOPE_AGENT)

__device__ __forceinline__ bf16x8 mkfrag(unsigned long long lo, unsigned long long hi) {
  union { unsigned long long q[2]; bf16x8 v; } u;
  u.q[0] = lo; u.q[1] = hi;
  return u.v;
}

__device__ __forceinline__ unsigned short f2bf(float f) {
  unsigned u = __float_as_uint(f);
  u += 0x7fffu + ((u >> 16) & 1u);   // round-to-nearest-even
  return (unsigned short)(u >> 16);
}
__device__ __forceinline__ float sigf(float x) { return 1.0f / (1.0f + __expf(-x)); }
__device__ __forceinline__ float tanhfast(float x) { return 1.0f - 2.0f / (1.0f + __expf(2.0f * x)); }

// ---- hierarchical grid barrier: 8 group counters -> root -> epoch broadcast ----
// bar layout (uints): grp g at g*32 (128 B apart); root at 256; epoch at 288.
// All coherent-visibility for h is provided by sc0sc1 stores + vmcnt(0) drain;
// no full-cache fences anywhere.
__device__ __forceinline__ void gbar2(unsigned* bar, int n, unsigned phase) {
  asm volatile("s_waitcnt vmcnt(0)" ::: "memory");  // sc-stores reached coherence point
  __syncthreads();
  if (threadIdx.x == 0) {
    unsigned* grp = bar + (n & 7) * 32;
    unsigned* root = bar + 256;
    unsigned* epoch = bar + 288;
    unsigned old = __hip_atomic_fetch_add(grp, 1u, __ATOMIC_RELEASE, __HIP_MEMORY_SCOPE_AGENT);
    if (old == phase * 16u - 1u) {                 // 16th arrival in group this phase
      unsigned r = __hip_atomic_fetch_add(root, 1u, __ATOMIC_RELEASE, __HIP_MEMORY_SCOPE_AGENT);
      if (r == phase * 8u - 1u)                    // 8th group this phase
        __hip_atomic_store(epoch, phase, __ATOMIC_RELAXED, __HIP_MEMORY_SCOPE_AGENT);
    }
    while (__hip_atomic_load(epoch, __ATOMIC_RELAXED, __HIP_MEMORY_SCOPE_AGENT) < phase)
      __builtin_amdgcn_s_sleep(1);
  }
  __syncthreads();
}

// ---- tokproj[v][n*32 + gate*8 + hu] = emb[v]@Wx + b  (block-local layout) ----
__global__ void __launch_bounds__(256)
tokproj_kernel(const float* __restrict__ emb,
               const float* __restrict__ Wgx, const float* __restrict__ Wix,
               const float* __restrict__ Wfx, const float* __restrict__ Wox,
               const float* __restrict__ bg, const float* __restrict__ bi,
               const float* __restrict__ bf_, const float* __restrict__ bo,
               float* __restrict__ tokproj) {
  __shared__ float esh[E_];
  const int v = blockIdx.x;
  const int c = blockIdx.y * 256 + threadIdx.x;
  const int gate = c >> 10;
  const int j = c & 1023;
  const float* W = (gate == 0) ? Wgx : (gate == 1) ? Wix : (gate == 2) ? Wfx : Wox;
  const float* bias = (gate == 0) ? bg : (gate == 1) ? bi : (gate == 2) ? bf_ : bo;
  esh[threadIdx.x] = emb[v * E_ + threadIdx.x];
  __syncthreads();
  float acc = bias[j];
#pragma unroll 4
  for (int e = 0; e < E_; ++e) acc += esh[e] * W[e * H_ + j];
  tokproj[v * 4096 + (j >> 3) * 32 + gate * 8 + (j & 7)] = acc;
}

// ---- WhT[c][k] = bf16(Wh_gate[k][j]) ; c = gate*1024 + j ----
__global__ void __launch_bounds__(256)
wht_kernel(const float* __restrict__ Wgh, const float* __restrict__ Wih,
           const float* __restrict__ Wfh, const float* __restrict__ Woh,
           unsigned short* __restrict__ WhT) {
  const int c = blockIdx.x;
  const int gate = c >> 10;
  const int j = c & 1023;
  const float* W = (gate == 0) ? Wgh : (gate == 1) ? Wih : (gate == 2) ? Wfh : Woh;
  for (int k = threadIdx.x; k < H_; k += 256)
    WhT[c * H_ + k] = f2bf(W[k * H_ + j]);
}

// ---- xT[s][b] = x[b][s] ----
__global__ void __launch_bounds__(256)
xpose_kernel(const int* __restrict__ x, int* __restrict__ xT) {
  const int id = blockIdx.x * 256 + threadIdx.x;  // 65536
  const int s = id >> 7, b = id & 127;
  xT[s * 128 + b] = x[b * S_ + s];
}

// ---- persistent scan: 128 blocks x 512 thr; block n owns hidden [n*8, n*8+8) ----
// waves 0-3: k in [0,512); waves 4-7: k in [512,1024). Partial Z summed in gate pass.
// All hbuf traffic is agent-scope atomic (sc0 sc1): coherent by construction.
__global__ void __launch_bounds__(512, 2)
lstm_scan(const int* __restrict__ xT, const float* __restrict__ tokproj,
          const unsigned short* __restrict__ WhT,
          unsigned short* __restrict__ hbuf, float* __restrict__ hfin,
          unsigned* __restrict__ bar) {
  extern __shared__ char smem[];
  unsigned short* Bsh = (unsigned short*)smem;                       // [128 kk][264]
  float* Zsh = (float*)(smem + BSH_BYTES);                           // [2][128][36]
  float* tsh = (float*)(smem + BSH_BYTES + ZSH_BYTES);               // [128][33]
  int* xsh = (int*)(smem + BSH_BYTES + ZSH_BYTES + TSH_BYTES);       // [128]

  const int n = blockIdx.x;
  const int tid = threadIdx.x;
  const int w = tid >> 6;
  const int g = w >> 2;           // k-group (0/1)
  const int wm = w & 3;           // m-group
  const int lane = tid & 63;
  const int l15 = lane & 15;
  const int lq = lane >> 4;

  // ---- one-time LDS fills (cached loads; L2 never invalidated -> stay warm) ----
  for (int it = tid; it < 4096; it += 512) {
    const int j = it >> 7, kk = it & 127;
    const int c = ((j >> 3) << 10) + n * 8 + (j & 7);
    *(uint4*)(Bsh + kk * BK_ROW + j * 8) = *(const uint4*)(WhT + c * 1024 + kk * 8);
  }
  for (int it = tid; it < 4096; it += 512) {
    const int v = it >> 5, off = it & 31;
    tsh[v * TSH_ROW + off] = tokproj[v * 4096 + n * 32 + off];
  }

  const int b_own = tid >> 2;        // batch row this thread owns in gate pass
  const int hu0 = (tid & 3) << 1;    // first of 2 hidden units
  const int col0 = n * 8 + hu0;      // global h column

  float creg[2] = {0.f, 0.f};
  __hip_atomic_store((unsigned*)(hbuf + b_own * H_ + col0), 0u,
                     __ATOMIC_RELAXED, __HIP_MEMORY_SCOPE_AGENT);  // zero h^{-1}

  unsigned phase = 1;
  gbar2(bar, n, phase);

  const int arow = wm * 32 + l15;
  const unsigned short* bbase = Bsh + (g * 64 + lq) * BK_ROW + l15 * 8;
  float* zb = Zsh + g * (128 * ZSH_ROW);

  for (int s = 0; s < S_; ++s) {
    const unsigned short* rd = hbuf + (s & 1) * (B_ * H_);
    unsigned short* wr = hbuf + ((s + 1) & 1) * (B_ * H_);

    if (tid < 128) xsh[tid] = xT[s * 128 + tid];

    const unsigned short* a0p = rd + arow * H_ + g * 512 + lq * 8;
    const unsigned short* a1p = a0p + 16 * H_;

    // issue ALL h-fragment loads up front (coherent 8B loads, full MLP)
    unsigned long long alo[8][4], ahi[8][4];
#pragma unroll
    for (int kt = 0; kt < 8; ++kt) {
      const unsigned short* p0 = a0p + kt * 64;
      const unsigned short* p1 = a1p + kt * 64;
      alo[kt][0] = ALD(p0);      ahi[kt][0] = ALD(p0 + 4);
      alo[kt][1] = ALD(p0 + 32); ahi[kt][1] = ALD(p0 + 36);
      alo[kt][2] = ALD(p1);      ahi[kt][2] = ALD(p1 + 4);
      alo[kt][3] = ALD(p1 + 32); ahi[kt][3] = ALD(p1 + 36);
    }

    f32x4 acc00 = {0.f, 0.f, 0.f, 0.f}, acc01 = {0.f, 0.f, 0.f, 0.f};
    f32x4 acc10 = {0.f, 0.f, 0.f, 0.f}, acc11 = {0.f, 0.f, 0.f, 0.f};

#pragma unroll
    for (int kt = 0; kt < 8; ++kt) {
      bf16x8 b00 = *(const bf16x8*)(bbase + (kt * 8) * BK_ROW);
      bf16x8 b01 = *(const bf16x8*)(bbase + (kt * 8) * BK_ROW + 128);
      bf16x8 b10 = *(const bf16x8*)(bbase + (kt * 8 + 4) * BK_ROW);
      bf16x8 b11 = *(const bf16x8*)(bbase + (kt * 8 + 4) * BK_ROW + 128);
      bf16x8 a00 = mkfrag(alo[kt][0], ahi[kt][0]);
      bf16x8 a01 = mkfrag(alo[kt][1], ahi[kt][1]);
      bf16x8 a10 = mkfrag(alo[kt][2], ahi[kt][2]);
      bf16x8 a11 = mkfrag(alo[kt][3], ahi[kt][3]);
      acc00 = __builtin_amdgcn_mfma_f32_16x16x32_bf16(a00, b00, acc00, 0, 0, 0);
      acc01 = __builtin_amdgcn_mfma_f32_16x16x32_bf16(a00, b01, acc01, 0, 0, 0);
      acc10 = __builtin_amdgcn_mfma_f32_16x16x32_bf16(a10, b00, acc10, 0, 0, 0);
      acc11 = __builtin_amdgcn_mfma_f32_16x16x32_bf16(a10, b01, acc11, 0, 0, 0);
      acc00 = __builtin_amdgcn_mfma_f32_16x16x32_bf16(a01, b10, acc00, 0, 0, 0);
      acc01 = __builtin_amdgcn_mfma_f32_16x16x32_bf16(a01, b11, acc01, 0, 0, 0);
      acc10 = __builtin_amdgcn_mfma_f32_16x16x32_bf16(a11, b10, acc10, 0, 0, 0);
      acc11 = __builtin_amdgcn_mfma_f32_16x16x32_bf16(a11, b11, acc11, 0, 0, 0);
    }

    // C/D layout: col = lane&15, row = (lane>>4)*4 + reg
#pragma unroll
    for (int r = 0; r < 4; ++r) {
      const int m0 = wm * 32 + lq * 4 + r;
      zb[m0 * ZSH_ROW + l15] = acc00[r];
      zb[m0 * ZSH_ROW + 16 + l15] = acc01[r];
      zb[(m0 + 16) * ZSH_ROW + l15] = acc10[r];
      zb[(m0 + 16) * ZSH_ROW + 16 + l15] = acc11[r];
    }
    __syncthreads();

    // gate pass: thread owns (b_own, hu0..hu0+1); z = partial0 + partial1
    {
      const int xb = xsh[b_own];
      const float* z0 = Zsh + b_own * ZSH_ROW;
      const float* z1 = z0 + 128 * ZSH_ROW;
      const float* tp = tsh + xb * TSH_ROW;
      float hv[2];
#pragma unroll
      for (int q = 0; q < 2; ++q) {
        const int i0 = hu0 + q;
        float gv = tanhfast(z0[i0] + z1[i0] + tp[i0]);
        float iv = sigf(z0[8 + i0] + z1[8 + i0] + tp[8 + i0]);
        float fv = sigf(z0[16 + i0] + z1[16 + i0] + tp[16 + i0]);
        float ov = sigf(z0[24 + i0] + z1[24 + i0] + tp[24 + i0]);
        creg[q] = gv * iv + creg[q] * fv;
        hv[q] = tanhfast(creg[q]) * ov;
      }
      const unsigned hp = (unsigned)f2bf(hv[0]) | ((unsigned)f2bf(hv[1]) << 16);
      __hip_atomic_store((unsigned*)(wr + b_own * H_ + col0), hp,
                         __ATOMIC_RELAXED, __HIP_MEMORY_SCOPE_AGENT);
      if (s == S_ - 1) {
        float2 h2; h2.x = hv[0]; h2.y = hv[1];
        *(float2*)(hfin + b_own * H_ + col0) = h2;
      }
    }
    ++phase;
    gbar2(bar, n, phase);
  }
}

// ---- p = hfin @ W_ph + b_p ; out = log_softmax(p) ----
__global__ void __launch_bounds__(256)
classify_kernel(const float* __restrict__ hfin, const float* __restrict__ Wph,
                const float* __restrict__ bp, float* __restrict__ out) {
  __shared__ float red[256 * 10];
  const int b = blockIdx.x, tid = threadIdx.x;
  float acc[10];
#pragma unroll
  for (int c = 0; c < 10; ++c) acc[c] = 0.f;
  for (int k = tid; k < H_; k += 256) {
    const float hv = hfin[b * H_ + k];
    const float* w = Wph + k * 10;
#pragma unroll
    for (int c = 0; c < 10; ++c) acc[c] += hv * w[c];
  }
#pragma unroll
  for (int c = 0; c < 10; ++c) red[tid * 10 + c] = acc[c];
  __syncthreads();
  for (int off = 128; off >= 1; off >>= 1) {
    if (tid < off) {
#pragma unroll
      for (int c = 0; c < 10; ++c) red[tid * 10 + c] += red[(tid + off) * 10 + c];
    }
    __syncthreads();
  }
  if (tid == 0) {
    float p[10];
    float m = -1e30f;
#pragma unroll
    for (int c = 0; c < 10; ++c) { p[c] = red[c] + bp[c]; m = fmaxf(m, p[c]); }
    float ssum = 0.f;
#pragma unroll
    for (int c = 0; c < 10; ++c) ssum += __expf(p[c] - m);
    const float lse = m + __logf(ssum);
#pragma unroll
    for (int c = 0; c < 10; ++c) out[b * 10 + c] = p[c] - lse;
  }
}

extern "C" void kernel_launch(void* const* d_in, const int* in_sizes, int n_in,
                              void* d_out, int out_size, void* d_ws, size_t ws_size,
                              hipStream_t stream) {
  (void)in_sizes; (void)n_in; (void)out_size; (void)ws_size;
  const int* x = (const int*)d_in[0];
  const float* emb = (const float*)d_in[1];
  const float* Wgx = (const float*)d_in[2];
  const float* Wgh = (const float*)d_in[3];
  const float* bg = (const float*)d_in[4];
  const float* Wix = (const float*)d_in[5];
  const float* Wih = (const float*)d_in[6];
  const float* bi = (const float*)d_in[7];
  const float* Wfx = (const float*)d_in[8];
  const float* Wfh = (const float*)d_in[9];
  const float* bf_ = (const float*)d_in[10];
  const float* Wox = (const float*)d_in[11];
  const float* Woh = (const float*)d_in[12];
  const float* bo = (const float*)d_in[13];
  const float* Wph = (const float*)d_in[14];
  const float* bp = (const float*)d_in[15];
  float* out = (float*)d_out;

  char* ws = (char*)d_ws;
  float* tokproj = (float*)ws;                                  // 2 MB
  unsigned short* WhT = (unsigned short*)(ws + 2097152);        // 8 MB
  unsigned short* hbuf = (unsigned short*)(ws + 10485760);      // 512 KB (2 bufs)
  float* hfin = (float*)(ws + 11010048);                        // 512 KB
  unsigned* bar = (unsigned*)(ws + 11534336);                   // 2 KB barrier area
  int* xT = (int*)(ws + 11538432);                              // 256 KB

  hipMemsetAsync(bar, 0, 2048, stream);
  hipFuncSetAttribute(reinterpret_cast<const void*>(lstm_scan),
                      hipFuncAttributeMaxDynamicSharedMemorySize, SMEM_TOTAL);

  tokproj_kernel<<<dim3(V_, 16), dim3(256), 0, stream>>>(
      emb, Wgx, Wix, Wfx, Wox, bg, bi, bf_, bo, tokproj);
  wht_kernel<<<dim3(4096), dim3(256), 0, stream>>>(Wgh, Wih, Wfh, Woh, WhT);
  xpose_kernel<<<dim3(256), dim3(256), 0, stream>>>(x, xT);
  lstm_scan<<<dim3(128), dim3(512), SMEM_TOTAL, stream>>>(
      xT, tokproj, WhT, hbuf, hfin, bar);
  classify_kernel<<<dim3(128), dim3(256), 0, stream>>>(hfin, Wph, bp, out);
}

// Round 5
// 8553.471 us; speedup vs baseline: 2.2763x; 1.0904x over previous
//
#include <hip/hip_runtime.h>

#define H_ 1024
#define B_ 128
#define S_ 512
#define V_ 128
#define E_ 256

#define BK_ROW 264              // bf16 elems per kk-row: 32 cols * 8 + 8 pad
#define ZSH_ROW 36              // 32 + 4 pad (f32)
#define TSH_ROW 33              // 32 + 1 pad (f32)
#define BSH_BYTES (128 * BK_ROW * 2)        // 67584
#define ZSH_BYTES (2 * 128 * ZSH_ROW * 4)   // 36864 (two k-group partials)
#define TSH_BYTES (128 * TSH_ROW * 4)       // 16896
#define SMEM_TOTAL (BSH_BYTES + ZSH_BYTES + TSH_BYTES + 512)  // 121856

typedef __bf16 bf16x8 __attribute__((ext_vector_type(8)));
typedef float f32x4 __attribute__((ext_vector_type(4)));

#define ALD(p) __hip_atomic_load((const unsigned long long*)(p), __ATOMIC_RELAXED, __HIP_MEMORY_SCOPE_AGENT)

__device__ __forceinline__ bf16x8 mkfrag(unsigned long long lo, unsigned long long hi) {
  union { unsigned long long q[2]; bf16x8 v; } u;
  u.q[0] = lo; u.q[1] = hi;
  return u.v;
}

__device__ __forceinline__ unsigned short f2bf(float f) {
  unsigned u = __float_as_uint(f);
  u += 0x7fffu + ((u >> 16) & 1u);   // round-to-nearest-even
  return (unsigned short)(u >> 16);
}
__device__ __forceinline__ float sigf(float x) { return 1.0f / (1.0f + __expf(-x)); }
__device__ __forceinline__ float tanhfast(float x) { return 1.0f - 2.0f / (1.0f + __expf(2.0f * x)); }

// ---- tokproj[v][n*32 + gate*8 + hu] = emb[v]@Wx + b  (block-local layout) ----
__global__ void __launch_bounds__(256)
tokproj_kernel(const float* __restrict__ emb,
               const float* __restrict__ Wgx, const float* __restrict__ Wix,
               const float* __restrict__ Wfx, const float* __restrict__ Wox,
               const float* __restrict__ bg, const float* __restrict__ bi,
               const float* __restrict__ bf_, const float* __restrict__ bo,
               float* __restrict__ tokproj) {
  __shared__ float esh[E_];
  const int v = blockIdx.x;
  const int c = blockIdx.y * 256 + threadIdx.x;
  const int gate = c >> 10;
  const int j = c & 1023;
  const float* W = (gate == 0) ? Wgx : (gate == 1) ? Wix : (gate == 2) ? Wfx : Wox;
  const float* bias = (gate == 0) ? bg : (gate == 1) ? bi : (gate == 2) ? bf_ : bo;
  esh[threadIdx.x] = emb[v * E_ + threadIdx.x];
  __syncthreads();
  float acc = bias[j];
#pragma unroll 4
  for (int e = 0; e < E_; ++e) acc += esh[e] * W[e * H_ + j];
  tokproj[v * 4096 + (j >> 3) * 32 + gate * 8 + (j & 7)] = acc;
}

// ---- WhT[c][k] = bf16(Wh_gate[k][j]) ; c = gate*1024 + j ----
__global__ void __launch_bounds__(256)
wht_kernel(const float* __restrict__ Wgh, const float* __restrict__ Wih,
           const float* __restrict__ Wfh, const float* __restrict__ Woh,
           unsigned short* __restrict__ WhT) {
  const int c = blockIdx.x;
  const int gate = c >> 10;
  const int j = c & 1023;
  const float* W = (gate == 0) ? Wgh : (gate == 1) ? Wih : (gate == 2) ? Wfh : Woh;
  for (int k = threadIdx.x; k < H_; k += 256)
    WhT[c * H_ + k] = f2bf(W[k * H_ + j]);
}

// ---- xT[s][b] = x[b][s] ----
__global__ void __launch_bounds__(256)
xpose_kernel(const int* __restrict__ x, int* __restrict__ xT) {
  const int id = blockIdx.x * 256 + threadIdx.x;  // 65536
  const int s = id >> 7, b = id & 127;
  xT[s * 128 + b] = x[b * S_ + s];
}

// ---- persistent scan: 128 blocks x 512 thr; block n owns hidden [n*8, n*8+8) ----
// Producer-consumer flags instead of a grid barrier: pub[m] (one cacheline each)
// counts versions of h published by block m (init h^0 counts as pub=1).
// Step s: wait all pub >= s+1, read buf(s&1), write buf((s+1)&1), publish s+2.
// Two buffers are safe: observing all pub>=s implies everyone finished reading s-1.
__global__ void __launch_bounds__(512, 2)
lstm_scan(const int* __restrict__ xT, const float* __restrict__ tokproj,
          const unsigned short* __restrict__ WhT,
          unsigned short* __restrict__ hbuf, float* __restrict__ hfin,
          unsigned* __restrict__ pub) {
  extern __shared__ char smem[];
  unsigned short* Bsh = (unsigned short*)smem;                       // [128 kk][264]
  float* Zsh = (float*)(smem + BSH_BYTES);                           // [2][128][36]
  float* tsh = (float*)(smem + BSH_BYTES + ZSH_BYTES);               // [128][33]
  int* xsh = (int*)(smem + BSH_BYTES + ZSH_BYTES + TSH_BYTES);       // [128]

  const int n = blockIdx.x;
  const int tid = threadIdx.x;
  const int w = tid >> 6;
  const int g = w >> 2;           // k-group (0/1)
  const int wm = w & 3;           // m-group
  const int lane = tid & 63;
  const int l15 = lane & 15;
  const int lq = lane >> 4;

  // ---- one-time LDS fills (cached loads; L2 never invalidated -> stay warm) ----
  for (int it = tid; it < 4096; it += 512) {
    const int j = it >> 7, kk = it & 127;
    const int c = ((j >> 3) << 10) + n * 8 + (j & 7);
    *(uint4*)(Bsh + kk * BK_ROW + j * 8) = *(const uint4*)(WhT + c * 1024 + kk * 8);
  }
  for (int it = tid; it < 4096; it += 512) {
    const int v = it >> 5, off = it & 31;
    tsh[v * TSH_ROW + off] = tokproj[v * 4096 + n * 32 + off];
  }

  const int b_own = tid >> 2;        // batch row this thread owns in gate pass
  const int hu0 = (tid & 3) << 1;    // first of 2 hidden units
  const int col0 = n * 8 + hu0;      // global h column

  float creg[2] = {0.f, 0.f};
  __hip_atomic_store((unsigned*)(hbuf + b_own * H_ + col0), 0u,
                     __ATOMIC_RELAXED, __HIP_MEMORY_SCOPE_AGENT);  // zero h^0
  asm volatile("s_waitcnt vmcnt(0)" ::: "memory");
  __syncthreads();
  if (tid == 0)
    __hip_atomic_store(pub + n * 32, 1u, __ATOMIC_RELAXED, __HIP_MEMORY_SCOPE_AGENT);

  const int arow = wm * 32 + l15;
  const unsigned short* bbase = Bsh + (g * 64 + lq) * BK_ROW + l15 * 8;
  float* zb = Zsh + g * (128 * ZSH_ROW);

  for (int s = 0; s < S_; ++s) {
    const unsigned short* rd = hbuf + (s & 1) * (B_ * H_);
    unsigned short* wr = hbuf + ((s + 1) & 1) * (B_ * H_);

    // distributed wait: thread m<128 polls producer m's flag (own flag skipped)
    if (tid < 128) {
      xsh[tid] = xT[s * 128 + tid];
      if (tid != n) {
        const unsigned tgt = (unsigned)(s + 1);
        while (__hip_atomic_load(pub + tid * 32, __ATOMIC_RELAXED,
                                 __HIP_MEMORY_SCOPE_AGENT) < tgt)
          __builtin_amdgcn_s_sleep(1);
      }
    }
    __syncthreads();

    const unsigned short* a0p = rd + arow * H_ + g * 512 + lq * 8;
    const unsigned short* a1p = a0p + 16 * H_;

    // issue ALL h-fragment loads up front (coherent 8B loads, full MLP)
    unsigned long long alo[8][4], ahi[8][4];
#pragma unroll
    for (int kt = 0; kt < 8; ++kt) {
      const unsigned short* p0 = a0p + kt * 64;
      const unsigned short* p1 = a1p + kt * 64;
      alo[kt][0] = ALD(p0);      ahi[kt][0] = ALD(p0 + 4);
      alo[kt][1] = ALD(p0 + 32); ahi[kt][1] = ALD(p0 + 36);
      alo[kt][2] = ALD(p1);      ahi[kt][2] = ALD(p1 + 4);
      alo[kt][3] = ALD(p1 + 32); ahi[kt][3] = ALD(p1 + 36);
    }

    f32x4 acc00 = {0.f, 0.f, 0.f, 0.f}, acc01 = {0.f, 0.f, 0.f, 0.f};
    f32x4 acc10 = {0.f, 0.f, 0.f, 0.f}, acc11 = {0.f, 0.f, 0.f, 0.f};

#pragma unroll
    for (int kt = 0; kt < 8; ++kt) {
      bf16x8 b00 = *(const bf16x8*)(bbase + (kt * 8) * BK_ROW);
      bf16x8 b01 = *(const bf16x8*)(bbase + (kt * 8) * BK_ROW + 128);
      bf16x8 b10 = *(const bf16x8*)(bbase + (kt * 8 + 4) * BK_ROW);
      bf16x8 b11 = *(const bf16x8*)(bbase + (kt * 8 + 4) * BK_ROW + 128);
      bf16x8 a00 = mkfrag(alo[kt][0], ahi[kt][0]);
      bf16x8 a01 = mkfrag(alo[kt][1], ahi[kt][1]);
      bf16x8 a10 = mkfrag(alo[kt][2], ahi[kt][2]);
      bf16x8 a11 = mkfrag(alo[kt][3], ahi[kt][3]);
      acc00 = __builtin_amdgcn_mfma_f32_16x16x32_bf16(a00, b00, acc00, 0, 0, 0);
      acc01 = __builtin_amdgcn_mfma_f32_16x16x32_bf16(a00, b01, acc01, 0, 0, 0);
      acc10 = __builtin_amdgcn_mfma_f32_16x16x32_bf16(a10, b00, acc10, 0, 0, 0);
      acc11 = __builtin_amdgcn_mfma_f32_16x16x32_bf16(a10, b01, acc11, 0, 0, 0);
      acc00 = __builtin_amdgcn_mfma_f32_16x16x32_bf16(a01, b10, acc00, 0, 0, 0);
      acc01 = __builtin_amdgcn_mfma_f32_16x16x32_bf16(a01, b11, acc01, 0, 0, 0);
      acc10 = __builtin_amdgcn_mfma_f32_16x16x32_bf16(a11, b10, acc10, 0, 0, 0);
      acc11 = __builtin_amdgcn_mfma_f32_16x16x32_bf16(a11, b11, acc11, 0, 0, 0);
    }

    // C/D layout: col = lane&15, row = (lane>>4)*4 + reg
#pragma unroll
    for (int r = 0; r < 4; ++r) {
      const int m0 = wm * 32 + lq * 4 + r;
      zb[m0 * ZSH_ROW + l15] = acc00[r];
      zb[m0 * ZSH_ROW + 16 + l15] = acc01[r];
      zb[(m0 + 16) * ZSH_ROW + l15] = acc10[r];
      zb[(m0 + 16) * ZSH_ROW + 16 + l15] = acc11[r];
    }
    __syncthreads();

    // gate pass: thread owns (b_own, hu0..hu0+1); z = partial0 + partial1
    {
      const int xb = xsh[b_own];
      const float* z0 = Zsh + b_own * ZSH_ROW;
      const float* z1 = z0 + 128 * ZSH_ROW;
      const float* tp = tsh + xb * TSH_ROW;
      float hv[2];
#pragma unroll
      for (int q = 0; q < 2; ++q) {
        const int i0 = hu0 + q;
        float gv = tanhfast(z0[i0] + z1[i0] + tp[i0]);
        float iv = sigf(z0[8 + i0] + z1[8 + i0] + tp[8 + i0]);
        float fv = sigf(z0[16 + i0] + z1[16 + i0] + tp[16 + i0]);
        float ov = sigf(z0[24 + i0] + z1[24 + i0] + tp[24 + i0]);
        creg[q] = gv * iv + creg[q] * fv;
        hv[q] = tanhfast(creg[q]) * ov;
      }
      const unsigned hp = (unsigned)f2bf(hv[0]) | ((unsigned)f2bf(hv[1]) << 16);
      __hip_atomic_store((unsigned*)(wr + b_own * H_ + col0), hp,
                         __ATOMIC_RELAXED, __HIP_MEMORY_SCOPE_AGENT);
      if (s == S_ - 1) {
        float2 h2; h2.x = hv[0]; h2.y = hv[1];
        *(float2*)(hfin + b_own * H_ + col0) = h2;
      }
    }
    // drain this block's h stores, then publish version s+1
    asm volatile("s_waitcnt vmcnt(0)" ::: "memory");
    __syncthreads();
    if (tid == 0)
      __hip_atomic_store(pub + n * 32, (unsigned)(s + 2),
                         __ATOMIC_RELAXED, __HIP_MEMORY_SCOPE_AGENT);
  }
}

// ---- p = hfin @ W_ph + b_p ; out = log_softmax(p) ----
__global__ void __launch_bounds__(256)
classify_kernel(const float* __restrict__ hfin, const float* __restrict__ Wph,
                const float* __restrict__ bp, float* __restrict__ out) {
  __shared__ float red[256 * 10];
  const int b = blockIdx.x, tid = threadIdx.x;
  float acc[10];
#pragma unroll
  for (int c = 0; c < 10; ++c) acc[c] = 0.f;
  for (int k = tid; k < H_; k += 256) {
    const float hv = hfin[b * H_ + k];
    const float* w = Wph + k * 10;
#pragma unroll
    for (int c = 0; c < 10; ++c) acc[c] += hv * w[c];
  }
#pragma unroll
  for (int c = 0; c < 10; ++c) red[tid * 10 + c] = acc[c];
  __syncthreads();
  for (int off = 128; off >= 1; off >>= 1) {
    if (tid < off) {
#pragma unroll
      for (int c = 0; c < 10; ++c) red[tid * 10 + c] += red[(tid + off) * 10 + c];
    }
    __syncthreads();
  }
  if (tid == 0) {
    float p[10];
    float m = -1e30f;
#pragma unroll
    for (int c = 0; c < 10; ++c) { p[c] = red[c] + bp[c]; m = fmaxf(m, p[c]); }
    float ssum = 0.f;
#pragma unroll
    for (int c = 0; c < 10; ++c) ssum += __expf(p[c] - m);
    const float lse = m + __logf(ssum);
#pragma unroll
    for (int c = 0; c < 10; ++c) out[b * 10 + c] = p[c] - lse;
  }
}

extern "C" void kernel_launch(void* const* d_in, const int* in_sizes, int n_in,
                              void* d_out, int out_size, void* d_ws, size_t ws_size,
                              hipStream_t stream) {
  (void)in_sizes; (void)n_in; (void)out_size; (void)ws_size;
  const int* x = (const int*)d_in[0];
  const float* emb = (const float*)d_in[1];
  const float* Wgx = (const float*)d_in[2];
  const float* Wgh = (const float*)d_in[3];
  const float* bg = (const float*)d_in[4];
  const float* Wix = (const float*)d_in[5];
  const float* Wih = (const float*)d_in[6];
  const float* bi = (const float*)d_in[7];
  const float* Wfx = (const float*)d_in[8];
  const float* Wfh = (const float*)d_in[9];
  const float* bf_ = (const float*)d_in[10];
  const float* Wox = (const float*)d_in[11];
  const float* Woh = (const float*)d_in[12];
  const float* bo = (const float*)d_in[13];
  const float* Wph = (const float*)d_in[14];
  const float* bp = (const float*)d_in[15];
  float* out = (float*)d_out;

  char* ws = (char*)d_ws;
  float* tokproj = (float*)ws;                                  // 2 MB
  unsigned short* WhT = (unsigned short*)(ws + 2097152);        // 8 MB
  unsigned short* hbuf = (unsigned short*)(ws + 10485760);      // 512 KB (2 bufs)
  float* hfin = (float*)(ws + 11010048);                        // 512 KB
  int* xT = (int*)(ws + 11538432);                              // 256 KB
  unsigned* pub = (unsigned*)(ws + 11800576);                   // 16 KB flags

  hipMemsetAsync(pub, 0, 16384, stream);
  hipFuncSetAttribute(reinterpret_cast<const void*>(lstm_scan),
                      hipFuncAttributeMaxDynamicSharedMemorySize, SMEM_TOTAL);

  tokproj_kernel<<<dim3(V_, 16), dim3(256), 0, stream>>>(
      emb, Wgx, Wix, Wfx, Wox, bg, bi, bf_, bo, tokproj);
  wht_kernel<<<dim3(4096), dim3(256), 0, stream>>>(Wgh, Wih, Wfh, Woh, WhT);
  xpose_kernel<<<dim3(256), dim3(256), 0, stream>>>(x, xT);
  lstm_scan<<<dim3(128), dim3(512), SMEM_TOTAL, stream>>>(
      xT, tokproj, WhT, hbuf, hfin, pub);
  classify_kernel<<<dim3(128), dim3(256), 0, stream>>>(hfin, Wph, bp, out);
}

// Round 7
// 5409.568 us; speedup vs baseline: 3.5993x; 1.5812x over previous
//
#include <hip/hip_runtime.h>

#define H_ 1024
#define B_ 128
#define S_ 512
#define V_ 128
#define E_ 256

#define BK_ROW 264              // bf16 elems per kk-row: 32 cols * 8 + 8 pad
#define ZSH_ROW 36              // 32 + 4 pad (f32)
#define TSH_ROW 33              // 32 + 1 pad (f32)
#define BSH_BYTES (128 * BK_ROW * 2)        // 67584
#define ZSH_BYTES (2 * 128 * ZSH_ROW * 4)   // 36864 (two k-group partials)
#define TSH_BYTES (128 * TSH_ROW * 4)       // 16896
#define SMEM_TOTAL (BSH_BYTES + ZSH_BYTES + TSH_BYTES + 512)  // 121856

typedef __bf16 bf16x8 __attribute__((ext_vector_type(8)));
typedef float f32x4 __attribute__((ext_vector_type(4)));

// Coherent (device-scope, L1/L2-bypass) but COALESCABLE 16-B load.
// Unlike __hip_atomic_load, this is a plain vector load with sc0 sc1 cache
// bits: the TA coalescer merges the 4 lanes sharing each 64-B line.
__device__ __forceinline__ uint4 cload16(const unsigned short* p) {
  uint4 r;
  asm volatile("global_load_dwordx4 %0, %1, off sc0 sc1"
               : "=v"(r) : "v"(p) : "memory");
  return r;
}

__device__ __forceinline__ unsigned short f2bf(float f) {
  unsigned u = __float_as_uint(f);
  u += 0x7fffu + ((u >> 16) & 1u);   // round-to-nearest-even
  return (unsigned short)(u >> 16);
}
__device__ __forceinline__ float sigf(float x) { return 1.0f / (1.0f + __expf(-x)); }
__device__ __forceinline__ float tanhfast(float x) { return 1.0f - 2.0f / (1.0f + __expf(2.0f * x)); }

// ---- tokproj[v][n*32 + gate*8 + hu] = emb[v]@Wx + b  (block-local layout) ----
__global__ void __launch_bounds__(256)
tokproj_kernel(const float* __restrict__ emb,
               const float* __restrict__ Wgx, const float* __restrict__ Wix,
               const float* __restrict__ Wfx, const float* __restrict__ Wox,
               const float* __restrict__ bg, const float* __restrict__ bi,
               const float* __restrict__ bf_, const float* __restrict__ bo,
               float* __restrict__ tokproj) {
  __shared__ float esh[E_];
  const int v = blockIdx.x;
  const int c = blockIdx.y * 256 + threadIdx.x;
  const int gate = c >> 10;
  const int j = c & 1023;
  const float* W = (gate == 0) ? Wgx : (gate == 1) ? Wix : (gate == 2) ? Wfx : Wox;
  const float* bias = (gate == 0) ? bg : (gate == 1) ? bi : (gate == 2) ? bf_ : bo;
  esh[threadIdx.x] = emb[v * E_ + threadIdx.x];
  __syncthreads();
  float acc = bias[j];
#pragma unroll 4
  for (int e = 0; e < E_; ++e) acc += esh[e] * W[e * H_ + j];
  tokproj[v * 4096 + (j >> 3) * 32 + gate * 8 + (j & 7)] = acc;
}

// ---- WhT[c][k] = bf16(Wh_gate[k][j]) ; c = gate*1024 + j ----
__global__ void __launch_bounds__(256)
wht_kernel(const float* __restrict__ Wgh, const float* __restrict__ Wih,
           const float* __restrict__ Wfh, const float* __restrict__ Woh,
           unsigned short* __restrict__ WhT) {
  const int c = blockIdx.x;
  const int gate = c >> 10;
  const int j = c & 1023;
  const float* W = (gate == 0) ? Wgh : (gate == 1) ? Wih : (gate == 2) ? Wfh : Woh;
  for (int k = threadIdx.x; k < H_; k += 256)
    WhT[c * H_ + k] = f2bf(W[k * H_ + j]);
}

// ---- xT[s][b] = x[b][s] ----
__global__ void __launch_bounds__(256)
xpose_kernel(const int* __restrict__ x, int* __restrict__ xT) {
  const int id = blockIdx.x * 256 + threadIdx.x;  // 65536
  const int s = id >> 7, b = id & 127;
  xT[s * 128 + b] = x[b * S_ + s];
}

// ---- persistent scan: 128 blocks x 512 thr; block n owns hidden [n*8, n*8+8) ----
// Producer-consumer flags: pub[m] counts versions of h published by block m.
// Step s: wait all pub >= s+1, read buf(s&1), write buf((s+1)&1), publish s+2.
__global__ void __launch_bounds__(512, 2)
lstm_scan(const int* __restrict__ xT, const float* __restrict__ tokproj,
          const unsigned short* __restrict__ WhT,
          unsigned short* __restrict__ hbuf, float* __restrict__ hfin,
          unsigned* __restrict__ pub) {
  extern __shared__ char smem[];
  unsigned short* Bsh = (unsigned short*)smem;                       // [128 kk][264]
  float* Zsh = (float*)(smem + BSH_BYTES);                           // [2][128][36]
  float* tsh = (float*)(smem + BSH_BYTES + ZSH_BYTES);               // [128][33]
  int* xsh = (int*)(smem + BSH_BYTES + ZSH_BYTES + TSH_BYTES);       // [128]

  const int n = blockIdx.x;
  const int tid = threadIdx.x;
  const int w = tid >> 6;
  const int g = w >> 2;           // k-group (0/1)
  const int wm = w & 3;           // m-group
  const int lane = tid & 63;
  const int l15 = lane & 15;
  const int lq = lane >> 4;

  // ---- one-time LDS fills (plain cached loads; read-only data stays L2-warm) ----
  for (int it = tid; it < 4096; it += 512) {
    const int j = it >> 7, kk = it & 127;
    const int c = ((j >> 3) << 10) + n * 8 + (j & 7);
    *(uint4*)(Bsh + kk * BK_ROW + j * 8) = *(const uint4*)(WhT + c * 1024 + kk * 8);
  }
  for (int it = tid; it < 4096; it += 512) {
    const int v = it >> 5, off = it & 31;
    tsh[v * TSH_ROW + off] = tokproj[v * 4096 + n * 32 + off];
  }

  const int b_own = tid >> 2;        // batch row this thread owns in gate pass
  const int hu0 = (tid & 3) << 1;    // first of 2 hidden units
  const int col0 = n * 8 + hu0;      // global h column

  float creg[2] = {0.f, 0.f};
  __hip_atomic_store((unsigned*)(hbuf + b_own * H_ + col0), 0u,
                     __ATOMIC_RELAXED, __HIP_MEMORY_SCOPE_AGENT);  // zero h^0
  asm volatile("s_waitcnt vmcnt(0)" ::: "memory");
  __syncthreads();
  if (tid == 0)
    __hip_atomic_store(pub + n * 32, 1u, __ATOMIC_RELAXED, __HIP_MEMORY_SCOPE_AGENT);

  const int arow = wm * 32 + l15;
  const unsigned short* bbase = Bsh + (g * 64 + lq) * BK_ROW + l15 * 8;
  float* zb = Zsh + g * (128 * ZSH_ROW);

  for (int s = 0; s < S_; ++s) {
    const unsigned short* rd = hbuf + (s & 1) * (B_ * H_);
    unsigned short* wr = hbuf + ((s + 1) & 1) * (B_ * H_);

    // distributed wait: thread m<128 polls producer m's flag (own flag skipped)
    if (tid < 128) {
      xsh[tid] = xT[s * 128 + tid];
      if (tid != n) {
        const unsigned tgt = (unsigned)(s + 1);
        while (__hip_atomic_load(pub + tid * 32, __ATOMIC_RELAXED,
                                 __HIP_MEMORY_SCOPE_AGENT) < tgt)
          __builtin_amdgcn_s_sleep(2);
      }
    }
    __syncthreads();

    const unsigned short* a0p = rd + arow * H_ + g * 512 + lq * 8;
    const unsigned short* a1p = a0p + 16 * H_;

    // issue ALL h-fragment loads up front as coalescable coherent dwordx4
    uint4 af[8][4];
#pragma unroll
    for (int kt = 0; kt < 8; ++kt) {
      af[kt][0] = cload16(a0p + kt * 64);
      af[kt][1] = cload16(a0p + kt * 64 + 32);
      af[kt][2] = cload16(a1p + kt * 64);
      af[kt][3] = cload16(a1p + kt * 64 + 32);
    }
    // asm loads are invisible to the compiler's waitcnt tracking: drain, block
    // scheduler motion across the drain, then pin each fragment component
    // (single-register ties) so every MFMA input depends on post-drain values.
    asm volatile("s_waitcnt vmcnt(0)" ::: "memory");
    __builtin_amdgcn_sched_barrier(0);
#pragma unroll
    for (int kt = 0; kt < 8; ++kt) {
#pragma unroll
      for (int i = 0; i < 4; ++i) {
        asm volatile("" : "+v"(af[kt][i].x), "+v"(af[kt][i].y),
                          "+v"(af[kt][i].z), "+v"(af[kt][i].w));
      }
    }

    f32x4 acc00 = {0.f, 0.f, 0.f, 0.f}, acc01 = {0.f, 0.f, 0.f, 0.f};
    f32x4 acc10 = {0.f, 0.f, 0.f, 0.f}, acc11 = {0.f, 0.f, 0.f, 0.f};

#pragma unroll
    for (int kt = 0; kt < 8; ++kt) {
      bf16x8 b00 = *(const bf16x8*)(bbase + (kt * 8) * BK_ROW);
      bf16x8 b01 = *(const bf16x8*)(bbase + (kt * 8) * BK_ROW + 128);
      bf16x8 b10 = *(const bf16x8*)(bbase + (kt * 8 + 4) * BK_ROW);
      bf16x8 b11 = *(const bf16x8*)(bbase + (kt * 8 + 4) * BK_ROW + 128);
      bf16x8 a00 = __builtin_bit_cast(bf16x8, af[kt][0]);
      bf16x8 a01 = __builtin_bit_cast(bf16x8, af[kt][1]);
      bf16x8 a10 = __builtin_bit_cast(bf16x8, af[kt][2]);
      bf16x8 a11 = __builtin_bit_cast(bf16x8, af[kt][3]);
      acc00 = __builtin_amdgcn_mfma_f32_16x16x32_bf16(a00, b00, acc00, 0, 0, 0);
      acc01 = __builtin_amdgcn_mfma_f32_16x16x32_bf16(a00, b01, acc01, 0, 0, 0);
      acc10 = __builtin_amdgcn_mfma_f32_16x16x32_bf16(a10, b00, acc10, 0, 0, 0);
      acc11 = __builtin_amdgcn_mfma_f32_16x16x32_bf16(a10, b01, acc11, 0, 0, 0);
      acc00 = __builtin_amdgcn_mfma_f32_16x16x32_bf16(a01, b10, acc00, 0, 0, 0);
      acc01 = __builtin_amdgcn_mfma_f32_16x16x32_bf16(a01, b11, acc01, 0, 0, 0);
      acc10 = __builtin_amdgcn_mfma_f32_16x16x32_bf16(a11, b10, acc10, 0, 0, 0);
      acc11 = __builtin_amdgcn_mfma_f32_16x16x32_bf16(a11, b11, acc11, 0, 0, 0);
    }

    // C/D layout: col = lane&15, row = (lane>>4)*4 + reg
#pragma unroll
    for (int r = 0; r < 4; ++r) {
      const int m0 = wm * 32 + lq * 4 + r;
      zb[m0 * ZSH_ROW + l15] = acc00[r];
      zb[m0 * ZSH_ROW + 16 + l15] = acc01[r];
      zb[(m0 + 16) * ZSH_ROW + l15] = acc10[r];
      zb[(m0 + 16) * ZSH_ROW + 16 + l15] = acc11[r];
    }
    __syncthreads();

    // gate pass: thread owns (b_own, hu0..hu0+1); z = partial0 + partial1
    {
      const int xb = xsh[b_own];
      const float* z0 = Zsh + b_own * ZSH_ROW;
      const float* z1 = z0 + 128 * ZSH_ROW;
      const float* tp = tsh + xb * TSH_ROW;
      float hv[2];
#pragma unroll
      for (int q = 0; q < 2; ++q) {
        const int i0 = hu0 + q;
        float gv = tanhfast(z0[i0] + z1[i0] + tp[i0]);
        float iv = sigf(z0[8 + i0] + z1[8 + i0] + tp[8 + i0]);
        float fv = sigf(z0[16 + i0] + z1[16 + i0] + tp[16 + i0]);
        float ov = sigf(z0[24 + i0] + z1[24 + i0] + tp[24 + i0]);
        creg[q] = gv * iv + creg[q] * fv;
        hv[q] = tanhfast(creg[q]) * ov;
      }
      const unsigned hp = (unsigned)f2bf(hv[0]) | ((unsigned)f2bf(hv[1]) << 16);
      __hip_atomic_store((unsigned*)(wr + b_own * H_ + col0), hp,
                         __ATOMIC_RELAXED, __HIP_MEMORY_SCOPE_AGENT);
      if (s == S_ - 1) {
        float2 h2; h2.x = hv[0]; h2.y = hv[1];
        *(float2*)(hfin + b_own * H_ + col0) = h2;
      }
    }
    // drain this block's h stores, then publish version s+1
    asm volatile("s_waitcnt vmcnt(0)" ::: "memory");
    __syncthreads();
    if (tid == 0)
      __hip_atomic_store(pub + n * 32, (unsigned)(s + 2),
                         __ATOMIC_RELAXED, __HIP_MEMORY_SCOPE_AGENT);
  }
}

// ---- p = hfin @ W_ph + b_p ; out = log_softmax(p) ----
__global__ void __launch_bounds__(256)
classify_kernel(const float* __restrict__ hfin, const float* __restrict__ Wph,
                const float* __restrict__ bp, float* __restrict__ out) {
  __shared__ float red[256 * 10];
  const int b = blockIdx.x, tid = threadIdx.x;
  float acc[10];
#pragma unroll
  for (int c = 0; c < 10; ++c) acc[c] = 0.f;
  for (int k = tid; k < H_; k += 256) {
    const float hv = hfin[b * H_ + k];
    const float* w = Wph + k * 10;
#pragma unroll
    for (int c = 0; c < 10; ++c) acc[c] += hv * w[c];
  }
#pragma unroll
  for (int c = 0; c < 10; ++c) red[tid * 10 + c] = acc[c];
  __syncthreads();
  for (int off = 128; off >= 1; off >>= 1) {
    if (tid < off) {
#pragma unroll
      for (int c = 0; c < 10; ++c) red[tid * 10 + c] += red[(tid + off) * 10 + c];
    }
    __syncthreads();
  }
  if (tid == 0) {
    float p[10];
    float m = -1e30f;
#pragma unroll
    for (int c = 0; c < 10; ++c) { p[c] = red[c] + bp[c]; m = fmaxf(m, p[c]); }
    float ssum = 0.f;
#pragma unroll
    for (int c = 0; c < 10; ++c) ssum += __expf(p[c] - m);
    const float lse = m + __logf(ssum);
#pragma unroll
    for (int c = 0; c < 10; ++c) out[b * 10 + c] = p[c] - lse;
  }
}

extern "C" void kernel_launch(void* const* d_in, const int* in_sizes, int n_in,
                              void* d_out, int out_size, void* d_ws, size_t ws_size,
                              hipStream_t stream) {
  (void)in_sizes; (void)n_in; (void)out_size; (void)ws_size;
  const int* x = (const int*)d_in[0];
  const float* emb = (const float*)d_in[1];
  const float* Wgx = (const float*)d_in[2];
  const float* Wgh = (const float*)d_in[3];
  const float* bg = (const float*)d_in[4];
  const float* Wix = (const float*)d_in[5];
  const float* Wih = (const float*)d_in[6];
  const float* bi = (const float*)d_in[7];
  const float* Wfx = (const float*)d_in[8];
  const float* Wfh = (const float*)d_in[9];
  const float* bf_ = (const float*)d_in[10];
  const float* Wox = (const float*)d_in[11];
  const float* Woh = (const float*)d_in[12];
  const float* bo = (const float*)d_in[13];
  const float* Wph = (const float*)d_in[14];
  const float* bp = (const float*)d_in[15];
  float* out = (float*)d_out;

  char* ws = (char*)d_ws;
  float* tokproj = (float*)ws;                                  // 2 MB
  unsigned short* WhT = (unsigned short*)(ws + 2097152);        // 8 MB
  unsigned short* hbuf = (unsigned short*)(ws + 10485760);      // 512 KB (2 bufs)
  float* hfin = (float*)(ws + 11010048);                        // 512 KB
  int* xT = (int*)(ws + 11538432);                              // 256 KB
  unsigned* pub = (unsigned*)(ws + 11800576);                   // 16 KB flags

  hipMemsetAsync(pub, 0, 16384, stream);
  hipFuncSetAttribute(reinterpret_cast<const void*>(lstm_scan),
                      hipFuncAttributeMaxDynamicSharedMemorySize, SMEM_TOTAL);

  tokproj_kernel<<<dim3(V_, 16), dim3(256), 0, stream>>>(
      emb, Wgx, Wix, Wfx, Wox, bg, bi, bf_, bo, tokproj);
  wht_kernel<<<dim3(4096), dim3(256), 0, stream>>>(Wgh, Wih, Wfh, Woh, WhT);
  xpose_kernel<<<dim3(256), dim3(256), 0, stream>>>(x, xT);
  lstm_scan<<<dim3(128), dim3(512), SMEM_TOTAL, stream>>>(
      xT, tokproj, WhT, hbuf, hfin, pub);
  classify_kernel<<<dim3(128), dim3(256), 0, stream>>>(hfin, Wph, bp, out);
}

// Round 8
// 3421.508 us; speedup vs baseline: 5.6906x; 1.5810x over previous
//
#include <hip/hip_runtime.h>

#define H_ 1024
#define B_ 128
#define S_ 512
#define V_ 128
#define E_ 256

#define BK_ROW 264              // bf16 elems per kk-row: 32 cols * 8 + 8 pad
#define ZSH_ROW 36              // 32 + 4 pad (f32)
#define TSH_ROW 33              // 32 + 1 pad (f32)
#define BSH_BYTES (128 * BK_ROW * 2)        // 67584
#define ZSH_BYTES (4 * 64 * ZSH_ROW * 4)    // 36864 (four k-group partials, 64 rows)
#define TSH_BYTES (128 * TSH_ROW * 4)       // 16896
#define SMEM_TOTAL (BSH_BYTES + ZSH_BYTES + TSH_BYTES + 512)  // 121856

typedef __bf16 bf16x8 __attribute__((ext_vector_type(8)));
typedef float f32x4 __attribute__((ext_vector_type(4)));

// Coherent (device-scope, L1/L2-bypass) 16-B load; plain vector load with
// sc0 sc1 cache bits. Costs ~1 lane-request/cyc at the TA (measured r5->r7).
__device__ __forceinline__ uint4 cload16(const unsigned short* p) {
  uint4 r;
  asm volatile("global_load_dwordx4 %0, %1, off sc0 sc1"
               : "=v"(r) : "v"(p) : "memory");
  return r;
}

__device__ __forceinline__ unsigned short f2bf(float f) {
  unsigned u = __float_as_uint(f);
  u += 0x7fffu + ((u >> 16) & 1u);   // round-to-nearest-even
  return (unsigned short)(u >> 16);
}
__device__ __forceinline__ float sigf(float x) { return 1.0f / (1.0f + __expf(-x)); }
__device__ __forceinline__ float tanhfast(float x) { return 1.0f - 2.0f / (1.0f + __expf(2.0f * x)); }

// ---- tokproj[v][n*32 + gate*8 + hu] = emb[v]@Wx + b  (block-local layout) ----
__global__ void __launch_bounds__(256)
tokproj_kernel(const float* __restrict__ emb,
               const float* __restrict__ Wgx, const float* __restrict__ Wix,
               const float* __restrict__ Wfx, const float* __restrict__ Wox,
               const float* __restrict__ bg, const float* __restrict__ bi,
               const float* __restrict__ bf_, const float* __restrict__ bo,
               float* __restrict__ tokproj) {
  __shared__ float esh[E_];
  const int v = blockIdx.x;
  const int c = blockIdx.y * 256 + threadIdx.x;
  const int gate = c >> 10;
  const int j = c & 1023;
  const float* W = (gate == 0) ? Wgx : (gate == 1) ? Wix : (gate == 2) ? Wfx : Wox;
  const float* bias = (gate == 0) ? bg : (gate == 1) ? bi : (gate == 2) ? bf_ : bo;
  esh[threadIdx.x] = emb[v * E_ + threadIdx.x];
  __syncthreads();
  float acc = bias[j];
#pragma unroll 4
  for (int e = 0; e < E_; ++e) acc += esh[e] * W[e * H_ + j];
  tokproj[v * 4096 + (j >> 3) * 32 + gate * 8 + (j & 7)] = acc;
}

// ---- WhT[c][k] = bf16(Wh_gate[k][j]) ; c = gate*1024 + j ----
__global__ void __launch_bounds__(256)
wht_kernel(const float* __restrict__ Wgh, const float* __restrict__ Wih,
           const float* __restrict__ Wfh, const float* __restrict__ Woh,
           unsigned short* __restrict__ WhT) {
  const int c = blockIdx.x;
  const int gate = c >> 10;
  const int j = c & 1023;
  const float* W = (gate == 0) ? Wgh : (gate == 1) ? Wih : (gate == 2) ? Wfh : Woh;
  for (int k = threadIdx.x; k < H_; k += 256)
    WhT[c * H_ + k] = f2bf(W[k * H_ + j]);
}

// ---- xT[s][b] = x[b][s] ----
__global__ void __launch_bounds__(256)
xpose_kernel(const int* __restrict__ x, int* __restrict__ xT) {
  const int id = blockIdx.x * 256 + threadIdx.x;  // 65536
  const int s = id >> 7, b = id & 127;
  xT[s * 128 + b] = x[b * S_ + s];
}

// ---- persistent scan: 256 blocks x 512 thr (1 per CU) ----
// Block bid: n = bid&127 owns gate-cols [n*32..) (8 hidden units);
// half = bid>>7 owns batch rows [half*64, half*64+64).
// Block writes h rows of its half x its 8 cols; waits only on the 128
// same-half producer flags (they cover all cols of its rows).
__global__ void __launch_bounds__(512, 1)
lstm_scan(const int* __restrict__ xT, const float* __restrict__ tokproj,
          const unsigned short* __restrict__ WhT,
          unsigned short* __restrict__ hbuf, float* __restrict__ hfin,
          unsigned* __restrict__ pub) {
  extern __shared__ char smem[];
  unsigned short* Bsh = (unsigned short*)smem;                       // [128 kk][264]
  float* Zsh = (float*)(smem + BSH_BYTES);                           // [4][64][36]
  float* tsh = (float*)(smem + BSH_BYTES + ZSH_BYTES);               // [128][33]
  int* xsh = (int*)(smem + BSH_BYTES + ZSH_BYTES + TSH_BYTES);       // [64]

  const int bid = blockIdx.x;
  const int n = bid & 127;
  const int half = bid >> 7;
  const int tid = threadIdx.x;
  const int w = tid >> 6;
  const int g = w >> 1;           // k-group 0..3 (256 k each)
  const int wm = w & 1;           // m-group 0..1 (32 rows each)
  const int lane = tid & 63;
  const int l15 = lane & 15;
  const int lq = lane >> 4;

  // ---- one-time LDS fills (plain cached loads) ----
  for (int it = tid; it < 4096; it += 512) {
    const int j = it >> 7, kk = it & 127;
    const int c = ((j >> 3) << 10) + n * 8 + (j & 7);
    *(uint4*)(Bsh + kk * BK_ROW + j * 8) = *(const uint4*)(WhT + c * 1024 + kk * 8);
  }
  for (int it = tid; it < 4096; it += 512) {
    const int v = it >> 5, off = it & 31;
    tsh[v * TSH_ROW + off] = tokproj[v * 4096 + n * 32 + off];
  }

  const int b_loc = tid >> 3;        // 0..63 local batch row
  const int iu = tid & 7;            // hidden unit 0..7
  const int brow = half * 64 + b_loc;
  const int colg = n * 8 + iu;

  float creg = 0.f;
  __hip_atomic_store((unsigned short*)(hbuf + brow * H_ + colg),
                     (unsigned short)0, __ATOMIC_RELAXED, __HIP_MEMORY_SCOPE_AGENT);
  asm volatile("s_waitcnt vmcnt(0)" ::: "memory");
  __syncthreads();
  if (tid == 0)
    __hip_atomic_store(pub + bid * 32, 1u, __ATOMIC_RELAXED, __HIP_MEMORY_SCOPE_AGENT);

  const int arow = half * 64 + wm * 32 + l15;
  const unsigned short* bbase = Bsh + (g * 32 + lq) * BK_ROW + l15 * 8;
  float* zb = Zsh + g * (64 * ZSH_ROW);

  for (int s = 0; s < S_; ++s) {
    const unsigned short* rd = hbuf + (s & 1) * (B_ * H_);
    unsigned short* wr = hbuf + ((s + 1) & 1) * (B_ * H_);

    if (tid < 64) xsh[tid] = xT[s * 128 + half * 64 + tid];
    // wait on the 128 same-half producers (they cover all cols of our rows)
    if (tid < 128 && tid != n) {
      const unsigned tgt = (unsigned)(s + 1);
      const unsigned* fl = pub + (half * 128 + tid) * 32;
      while (__hip_atomic_load(fl, __ATOMIC_RELAXED, __HIP_MEMORY_SCOPE_AGENT) < tgt)
        __builtin_amdgcn_s_sleep(2);
    }
    __syncthreads();

    const unsigned short* a0p = rd + arow * H_ + g * 256 + lq * 8;
    const unsigned short* a1p = a0p + 16 * H_;

    // 16 coherent dwordx4 loads per thread (8192 lane-requests per block/CU)
    uint4 af[4][4];
#pragma unroll
    for (int kt = 0; kt < 4; ++kt) {
      af[kt][0] = cload16(a0p + kt * 64);
      af[kt][1] = cload16(a0p + kt * 64 + 32);
      af[kt][2] = cload16(a1p + kt * 64);
      af[kt][3] = cload16(a1p + kt * 64 + 32);
    }
    asm volatile("s_waitcnt vmcnt(0)" ::: "memory");
    __builtin_amdgcn_sched_barrier(0);
#pragma unroll
    for (int kt = 0; kt < 4; ++kt) {
#pragma unroll
      for (int i = 0; i < 4; ++i) {
        asm volatile("" : "+v"(af[kt][i].x), "+v"(af[kt][i].y),
                          "+v"(af[kt][i].z), "+v"(af[kt][i].w));
      }
    }

    f32x4 acc00 = {0.f, 0.f, 0.f, 0.f}, acc01 = {0.f, 0.f, 0.f, 0.f};
    f32x4 acc10 = {0.f, 0.f, 0.f, 0.f}, acc11 = {0.f, 0.f, 0.f, 0.f};

#pragma unroll
    for (int kt = 0; kt < 4; ++kt) {
      bf16x8 b00 = *(const bf16x8*)(bbase + (kt * 8) * BK_ROW);
      bf16x8 b01 = *(const bf16x8*)(bbase + (kt * 8) * BK_ROW + 128);
      bf16x8 b10 = *(const bf16x8*)(bbase + (kt * 8 + 4) * BK_ROW);
      bf16x8 b11 = *(const bf16x8*)(bbase + (kt * 8 + 4) * BK_ROW + 128);
      bf16x8 a00 = __builtin_bit_cast(bf16x8, af[kt][0]);
      bf16x8 a01 = __builtin_bit_cast(bf16x8, af[kt][1]);
      bf16x8 a10 = __builtin_bit_cast(bf16x8, af[kt][2]);
      bf16x8 a11 = __builtin_bit_cast(bf16x8, af[kt][3]);
      acc00 = __builtin_amdgcn_mfma_f32_16x16x32_bf16(a00, b00, acc00, 0, 0, 0);
      acc01 = __builtin_amdgcn_mfma_f32_16x16x32_bf16(a00, b01, acc01, 0, 0, 0);
      acc10 = __builtin_amdgcn_mfma_f32_16x16x32_bf16(a10, b00, acc10, 0, 0, 0);
      acc11 = __builtin_amdgcn_mfma_f32_16x16x32_bf16(a10, b01, acc11, 0, 0, 0);
      acc00 = __builtin_amdgcn_mfma_f32_16x16x32_bf16(a01, b10, acc00, 0, 0, 0);
      acc01 = __builtin_amdgcn_mfma_f32_16x16x32_bf16(a01, b11, acc01, 0, 0, 0);
      acc10 = __builtin_amdgcn_mfma_f32_16x16x32_bf16(a11, b10, acc10, 0, 0, 0);
      acc11 = __builtin_amdgcn_mfma_f32_16x16x32_bf16(a11, b11, acc11, 0, 0, 0);
    }

    // C/D layout: col = lane&15, row = (lane>>4)*4 + reg  (rows local 0..63)
#pragma unroll
    for (int r = 0; r < 4; ++r) {
      const int m0 = wm * 32 + lq * 4 + r;
      zb[m0 * ZSH_ROW + l15] = acc00[r];
      zb[m0 * ZSH_ROW + 16 + l15] = acc01[r];
      zb[(m0 + 16) * ZSH_ROW + l15] = acc10[r];
      zb[(m0 + 16) * ZSH_ROW + 16 + l15] = acc11[r];
    }
    __syncthreads();

    // gate pass: thread owns (b_loc, iu); z = sum of 4 k-group partials
    {
      const int xb = xsh[b_loc];
      const float* z0 = Zsh + b_loc * ZSH_ROW;
      const float* tp = tsh + xb * TSH_ROW;
      float zg = tp[iu], zi = tp[8 + iu], zf = tp[16 + iu], zo = tp[24 + iu];
#pragma unroll
      for (int gg = 0; gg < 4; ++gg) {
        const float* zp = z0 + gg * (64 * ZSH_ROW);
        zg += zp[iu]; zi += zp[8 + iu]; zf += zp[16 + iu]; zo += zp[24 + iu];
      }
      const float gv = tanhfast(zg);
      const float iv = sigf(zi);
      const float fv = sigf(zf);
      const float ov = sigf(zo);
      creg = gv * iv + creg * fv;
      const float hv = tanhfast(creg) * ov;
      __hip_atomic_store((unsigned short*)(wr + brow * H_ + colg), f2bf(hv),
                         __ATOMIC_RELAXED, __HIP_MEMORY_SCOPE_AGENT);
      if (s == S_ - 1) hfin[brow * H_ + colg] = hv;
    }
    // drain this block's h stores, then publish version s+1
    asm volatile("s_waitcnt vmcnt(0)" ::: "memory");
    __syncthreads();
    if (tid == 0)
      __hip_atomic_store(pub + bid * 32, (unsigned)(s + 2),
                         __ATOMIC_RELAXED, __HIP_MEMORY_SCOPE_AGENT);
  }
}

// ---- p = hfin @ W_ph + b_p ; out = log_softmax(p) ----
__global__ void __launch_bounds__(256)
classify_kernel(const float* __restrict__ hfin, const float* __restrict__ Wph,
                const float* __restrict__ bp, float* __restrict__ out) {
  __shared__ float red[256 * 10];
  const int b = blockIdx.x, tid = threadIdx.x;
  float acc[10];
#pragma unroll
  for (int c = 0; c < 10; ++c) acc[c] = 0.f;
  for (int k = tid; k < H_; k += 256) {
    const float hv = hfin[b * H_ + k];
    const float* w = Wph + k * 10;
#pragma unroll
    for (int c = 0; c < 10; ++c) acc[c] += hv * w[c];
  }
#pragma unroll
  for (int c = 0; c < 10; ++c) red[tid * 10 + c] = acc[c];
  __syncthreads();
  for (int off = 128; off >= 1; off >>= 1) {
    if (tid < off) {
#pragma unroll
      for (int c = 0; c < 10; ++c) red[tid * 10 + c] += red[(tid + off) * 10 + c];
    }
    __syncthreads();
  }
  if (tid == 0) {
    float p[10];
    float m = -1e30f;
#pragma unroll
    for (int c = 0; c < 10; ++c) { p[c] = red[c] + bp[c]; m = fmaxf(m, p[c]); }
    float ssum = 0.f;
#pragma unroll
    for (int c = 0; c < 10; ++c) ssum += __expf(p[c] - m);
    const float lse = m + __logf(ssum);
#pragma unroll
    for (int c = 0; c < 10; ++c) out[b * 10 + c] = p[c] - lse;
  }
}

extern "C" void kernel_launch(void* const* d_in, const int* in_sizes, int n_in,
                              void* d_out, int out_size, void* d_ws, size_t ws_size,
                              hipStream_t stream) {
  (void)in_sizes; (void)n_in; (void)out_size; (void)ws_size;
  const int* x = (const int*)d_in[0];
  const float* emb = (const float*)d_in[1];
  const float* Wgx = (const float*)d_in[2];
  const float* Wgh = (const float*)d_in[3];
  const float* bg = (const float*)d_in[4];
  const float* Wix = (const float*)d_in[5];
  const float* Wih = (const float*)d_in[6];
  const float* bi = (const float*)d_in[7];
  const float* Wfx = (const float*)d_in[8];
  const float* Wfh = (const float*)d_in[9];
  const float* bf_ = (const float*)d_in[10];
  const float* Wox = (const float*)d_in[11];
  const float* Woh = (const float*)d_in[12];
  const float* bo = (const float*)d_in[13];
  const float* Wph = (const float*)d_in[14];
  const float* bp = (const float*)d_in[15];
  float* out = (float*)d_out;

  char* ws = (char*)d_ws;
  float* tokproj = (float*)ws;                                  // 2 MB
  unsigned short* WhT = (unsigned short*)(ws + 2097152);        // 8 MB
  unsigned short* hbuf = (unsigned short*)(ws + 10485760);      // 512 KB (2 bufs)
  float* hfin = (float*)(ws + 11010048);                        // 512 KB
  int* xT = (int*)(ws + 11538432);                              // 256 KB
  unsigned* pub = (unsigned*)(ws + 11800576);                   // 32 KB flags

  hipMemsetAsync(pub, 0, 32768, stream);
  hipFuncSetAttribute(reinterpret_cast<const void*>(lstm_scan),
                      hipFuncAttributeMaxDynamicSharedMemorySize, SMEM_TOTAL);

  tokproj_kernel<<<dim3(V_, 16), dim3(256), 0, stream>>>(
      emb, Wgx, Wix, Wfx, Wox, bg, bi, bf_, bo, tokproj);
  wht_kernel<<<dim3(4096), dim3(256), 0, stream>>>(Wgh, Wih, Wfh, Woh, WhT);
  xpose_kernel<<<dim3(256), dim3(256), 0, stream>>>(x, xT);
  lstm_scan<<<dim3(256), dim3(512), SMEM_TOTAL, stream>>>(
      xT, tokproj, WhT, hbuf, hfin, pub);
  classify_kernel<<<dim3(128), dim3(256), 0, stream>>>(hfin, Wph, bp, out);
}

// Round 9
// 1841.947 us; speedup vs baseline: 10.5706x; 1.8575x over previous
//
#include <hip/hip_runtime.h>

#define H_ 1024
#define B_ 128
#define S_ 512
#define V_ 128
#define E_ 256

// LDS layout (bytes): Ash 32768 | Zsh 33792 | tsh 67584 | xsh 64
#define ASH_OFF 0
#define ZSH_OFF 32768
#define TSH_OFF 66560
#define XSH_OFF 134144
#define SMEM_TOTAL 134208

typedef __bf16 bf16x8 __attribute__((ext_vector_type(8)));
typedef float f32x4 __attribute__((ext_vector_type(4)));

// Coherent (device-scope, L1/L2-bypass) 16-B load; ~1 lane-request/cyc at the
// CU (validated r7->r8: step time scales linearly with per-CU request count).
__device__ __forceinline__ uint4 cload16(const unsigned short* p) {
  uint4 r;
  asm volatile("global_load_dwordx4 %0, %1, off sc0 sc1"
               : "=v"(r) : "v"(p) : "memory");
  return r;
}

__device__ __forceinline__ unsigned short f2bf(float f) {
  unsigned u = __float_as_uint(f);
  u += 0x7fffu + ((u >> 16) & 1u);   // round-to-nearest-even
  return (unsigned short)(u >> 16);
}
__device__ __forceinline__ float sigf(float x) { return 1.0f / (1.0f + __expf(-x)); }
__device__ __forceinline__ float tanhfast(float x) { return 1.0f - 2.0f / (1.0f + __expf(2.0f * x)); }

// ---- tokproj[v][c] = emb[v]@Wx + b ; c = gate*1024 + j (natural layout) ----
__global__ void __launch_bounds__(256)
tokproj_kernel(const float* __restrict__ emb,
               const float* __restrict__ Wgx, const float* __restrict__ Wix,
               const float* __restrict__ Wfx, const float* __restrict__ Wox,
               const float* __restrict__ bg, const float* __restrict__ bi,
               const float* __restrict__ bf_, const float* __restrict__ bo,
               float* __restrict__ tokproj) {
  __shared__ float esh[E_];
  const int v = blockIdx.x;
  const int c = blockIdx.y * 256 + threadIdx.x;
  const int gate = c >> 10;
  const int j = c & 1023;
  const float* W = (gate == 0) ? Wgx : (gate == 1) ? Wix : (gate == 2) ? Wfx : Wox;
  const float* bias = (gate == 0) ? bg : (gate == 1) ? bi : (gate == 2) ? bf_ : bo;
  esh[threadIdx.x] = emb[v * E_ + threadIdx.x];
  __syncthreads();
  float acc = bias[j];
#pragma unroll 4
  for (int e = 0; e < E_; ++e) acc += esh[e] * W[e * H_ + j];
  tokproj[v * 4096 + c] = acc;
}

// ---- WhT[c][k] = bf16(Wh_gate[k][j]) ; c = gate*1024 + j ----
__global__ void __launch_bounds__(256)
wht_kernel(const float* __restrict__ Wgh, const float* __restrict__ Wih,
           const float* __restrict__ Wfh, const float* __restrict__ Woh,
           unsigned short* __restrict__ WhT) {
  const int c = blockIdx.x;
  const int gate = c >> 10;
  const int j = c & 1023;
  const float* W = (gate == 0) ? Wgh : (gate == 1) ? Wih : (gate == 2) ? Wfh : Woh;
  for (int k = threadIdx.x; k < H_; k += 256)
    WhT[c * H_ + k] = f2bf(W[k * H_ + j]);
}

// ---- xT[s][b] = x[b][s] ----
__global__ void __launch_bounds__(256)
xpose_kernel(const int* __restrict__ x, int* __restrict__ xT) {
  const int id = blockIdx.x * 256 + threadIdx.x;  // 65536
  const int s = id >> 7, b = id & 127;
  xT[s * 128 + b] = x[b * S_ + s];
}

// ---- persistent scan: 256 blocks x 512 thr (1 per CU) ----
// bid: rg = bid>>5 owns batch rows [rg*16, rg*16+16); cg = bid&31 owns hidden
// units [cg*32, cg*32+32) (128 gate-cols). Per step the block reads 16 rows x
// 1024 k of h (2048 lane-requests), computes z (K split 4-way over wave
// pairs), updates c/h for its 16x32 region, publishes. Consumers wait only on
// the 32 same-rg producer flags (they cover all cols of their rows).
__global__ void __launch_bounds__(512, 1)
lstm_scan(const int* __restrict__ xT, const float* __restrict__ tokproj,
          const unsigned short* __restrict__ WhT,
          unsigned short* __restrict__ hbuf, float* __restrict__ hfin,
          unsigned* __restrict__ pub) {
  extern __shared__ char smem[];
  char* AshB = smem + ASH_OFF;                 // A fragment-major, XOR-swizzled
  float* Zsh = (float*)(smem + ZSH_OFF);       // [4 kg][16 row][132]
  float* tsh = (float*)(smem + TSH_OFF);       // [128 v][132]
  int* xsh = (int*)(smem + XSH_OFF);           // [16]

  const int bid = blockIdx.x;
  const int rg = bid >> 5;
  const int cg = bid & 31;
  const int tid = threadIdx.x;
  const int w = tid >> 6;
  const int kg = w >> 1;          // k-group 0..3 (256 k each)
  const int ch = w & 1;           // col-half 0..1 (64 gate-cols each)
  const int lane = tid & 63;
  const int l15 = lane & 15;
  const int lq = lane >> 4;

  // ---- one-time: tokproj slice -> LDS (block-local col j = gate*32+hu) ----
  for (int it = tid; it < 16384; it += 512) {
    const int v = it >> 7, j = it & 127;
    tsh[v * 132 + j] = tokproj[v * 4096 + (j >> 5) * 1024 + cg * 32 + (j & 31)];
  }
  // ---- one-time: B fragments -> registers (128 VGPRs) ----
  // wave w covers cols j = ch*64 + t*16 + l15, k = (kg*8+kc)*32 + lq*8
  uint4 breg[32];
#pragma unroll
  for (int kc = 0; kc < 8; ++kc) {
#pragma unroll
    for (int t = 0; t < 4; ++t) {
      const int j = ch * 64 + t * 16 + l15;
      const int c = ((j >> 5) << 10) + cg * 32 + (j & 31);
      breg[kc * 4 + t] =
          *(const uint4*)(WhT + c * 1024 + (kg * 8 + kc) * 32 + lq * 8);
    }
  }

  const int row_own = tid >> 5;      // 0..15
  const int hu = tid & 31;           // 0..31
  const int brow = rg * 16 + row_own;
  const int colg = cg * 32 + hu;

  float creg = 0.f;
  __hip_atomic_store((unsigned short*)(hbuf + brow * H_ + colg),
                     (unsigned short)0, __ATOMIC_RELAXED, __HIP_MEMORY_SCOPE_AGENT);
  asm volatile("s_waitcnt vmcnt(0)" ::: "memory");
  __syncthreads();
  if (tid == 0)
    __hip_atomic_store(pub + bid * 32, 1u, __ATOMIC_RELAXED, __HIP_MEMORY_SCOPE_AGENT);

  for (int s = 0; s < S_; ++s) {
    const unsigned short* rd = hbuf + (s & 1) * (B_ * H_);
    unsigned short* wr = hbuf + ((s + 1) & 1) * (B_ * H_);

    // wait on the 32 same-rg producers; 16 other threads fetch tokens
    if (tid < 32) {
      if (tid != cg) {
        const unsigned tgt = (unsigned)(s + 1);
        const unsigned* fl = pub + (rg * 32 + tid) * 32;
        while (__hip_atomic_load(fl, __ATOMIC_RELAXED, __HIP_MEMORY_SCOPE_AGENT) < tgt)
          __builtin_amdgcn_s_sleep(2);
      }
    } else if (tid >= 64 && tid < 80) {
      xsh[tid - 64] = xT[s * 128 + rg * 16 + (tid - 64)];
    }
    __syncthreads();

    // ---- stage A (16 rows x 1024 k) to LDS, fragment-major + XOR swizzle ----
    // chunk ci covers row = ci>>7, k-bytes (ci&127)*16; fragment f = ci&127.
    uint4 av[4];
#pragma unroll
    for (int i = 0; i < 4; ++i) {
      const int ci = i * 512 + tid;
      av[i] = cload16(rd + (rg * 16 + (ci >> 7)) * H_ + (ci & 127) * 8);
    }
    asm volatile("s_waitcnt vmcnt(0)" ::: "memory");
    __builtin_amdgcn_sched_barrier(0);
#pragma unroll
    for (int i = 0; i < 4; ++i) {
      asm volatile("" : "+v"(av[i].x), "+v"(av[i].y), "+v"(av[i].z), "+v"(av[i].w));
    }
#pragma unroll
    for (int i = 0; i < 4; ++i) {
      const int ci = i * 512 + tid;
      const int f = ci & 127, r = ci >> 7;
      *(uint4*)(AshB + f * 256 + ((r ^ (f & 15)) << 4)) = av[i];
    }
    __syncthreads();

    // ---- MFMA: wave covers k [kg*256, kg*256+256) x cols [ch*64, ch*64+64) ----
    f32x4 acc0 = {0.f, 0.f, 0.f, 0.f}, acc1 = {0.f, 0.f, 0.f, 0.f};
    f32x4 acc2 = {0.f, 0.f, 0.f, 0.f}, acc3 = {0.f, 0.f, 0.f, 0.f};
#pragma unroll
    for (int kc = 0; kc < 8; ++kc) {
      const int f = (kg * 8 + kc) * 4 + lq;
      bf16x8 a = *(const bf16x8*)(AshB + f * 256 + ((l15 ^ (f & 15)) << 4));
      acc0 = __builtin_amdgcn_mfma_f32_16x16x32_bf16(a, __builtin_bit_cast(bf16x8, breg[kc * 4 + 0]), acc0, 0, 0, 0);
      acc1 = __builtin_amdgcn_mfma_f32_16x16x32_bf16(a, __builtin_bit_cast(bf16x8, breg[kc * 4 + 1]), acc1, 0, 0, 0);
      acc2 = __builtin_amdgcn_mfma_f32_16x16x32_bf16(a, __builtin_bit_cast(bf16x8, breg[kc * 4 + 2]), acc2, 0, 0, 0);
      acc3 = __builtin_amdgcn_mfma_f32_16x16x32_bf16(a, __builtin_bit_cast(bf16x8, breg[kc * 4 + 3]), acc3, 0, 0, 0);
    }
    // C/D: col = lane&15 (block-col ch*64 + t*16 + l15), row = lq*4 + r_
#pragma unroll
    for (int r_ = 0; r_ < 4; ++r_) {
      float* zr = Zsh + (kg * 16 + lq * 4 + r_) * 132 + ch * 64 + l15;
      zr[0] = acc0[r_]; zr[16] = acc1[r_]; zr[32] = acc2[r_]; zr[48] = acc3[r_];
    }
    __syncthreads();

    // ---- gate pass: thread owns (row_own, hu); z = tok + sum of 4 partials ----
    {
      const int xb = xsh[row_own];
      const float* tp = tsh + xb * 132;
      float z[4];
#pragma unroll
      for (int gate = 0; gate < 4; ++gate) {
        float zz = tp[gate * 32 + hu];
#pragma unroll
        for (int kgg = 0; kgg < 4; ++kgg)
          zz += Zsh[(kgg * 16 + row_own) * 132 + gate * 32 + hu];
        z[gate] = zz;
      }
      const float gv = tanhfast(z[0]);
      const float iv = sigf(z[1]);
      const float fv = sigf(z[2]);
      const float ov = sigf(z[3]);
      creg = gv * iv + creg * fv;
      const float hv = tanhfast(creg) * ov;
      __hip_atomic_store((unsigned short*)(wr + brow * H_ + colg), f2bf(hv),
                         __ATOMIC_RELAXED, __HIP_MEMORY_SCOPE_AGENT);
      if (s == S_ - 1) hfin[brow * H_ + colg] = hv;
    }
    asm volatile("s_waitcnt vmcnt(0)" ::: "memory");
    __syncthreads();
    if (tid == 0)
      __hip_atomic_store(pub + bid * 32, (unsigned)(s + 2),
                         __ATOMIC_RELAXED, __HIP_MEMORY_SCOPE_AGENT);
  }
}

// ---- p = hfin @ W_ph + b_p ; out = log_softmax(p) ----
__global__ void __launch_bounds__(256)
classify_kernel(const float* __restrict__ hfin, const float* __restrict__ Wph,
                const float* __restrict__ bp, float* __restrict__ out) {
  __shared__ float red[256 * 10];
  const int b = blockIdx.x, tid = threadIdx.x;
  float acc[10];
#pragma unroll
  for (int c = 0; c < 10; ++c) acc[c] = 0.f;
  for (int k = tid; k < H_; k += 256) {
    const float hv = hfin[b * H_ + k];
    const float* w = Wph + k * 10;
#pragma unroll
    for (int c = 0; c < 10; ++c) acc[c] += hv * w[c];
  }
#pragma unroll
  for (int c = 0; c < 10; ++c) red[tid * 10 + c] = acc[c];
  __syncthreads();
  for (int off = 128; off >= 1; off >>= 1) {
    if (tid < off) {
#pragma unroll
      for (int c = 0; c < 10; ++c) red[tid * 10 + c] += red[(tid + off) * 10 + c];
    }
    __syncthreads();
  }
  if (tid == 0) {
    float p[10];
    float m = -1e30f;
#pragma unroll
    for (int c = 0; c < 10; ++c) { p[c] = red[c] + bp[c]; m = fmaxf(m, p[c]); }
    float ssum = 0.f;
#pragma unroll
    for (int c = 0; c < 10; ++c) ssum += __expf(p[c] - m);
    const float lse = m + __logf(ssum);
#pragma unroll
    for (int c = 0; c < 10; ++c) out[b * 10 + c] = p[c] - lse;
  }
}

extern "C" void kernel_launch(void* const* d_in, const int* in_sizes, int n_in,
                              void* d_out, int out_size, void* d_ws, size_t ws_size,
                              hipStream_t stream) {
  (void)in_sizes; (void)n_in; (void)out_size; (void)ws_size;
  const int* x = (const int*)d_in[0];
  const float* emb = (const float*)d_in[1];
  const float* Wgx = (const float*)d_in[2];
  const float* Wgh = (const float*)d_in[3];
  const float* bg = (const float*)d_in[4];
  const float* Wix = (const float*)d_in[5];
  const float* Wih = (const float*)d_in[6];
  const float* bi = (const float*)d_in[7];
  const float* Wfx = (const float*)d_in[8];
  const float* Wfh = (const float*)d_in[9];
  const float* bf_ = (const float*)d_in[10];
  const float* Wox = (const float*)d_in[11];
  const float* Woh = (const float*)d_in[12];
  const float* bo = (const float*)d_in[13];
  const float* Wph = (const float*)d_in[14];
  const float* bp = (const float*)d_in[15];
  float* out = (float*)d_out;

  char* ws = (char*)d_ws;
  float* tokproj = (float*)ws;                                  // 2 MB
  unsigned short* WhT = (unsigned short*)(ws + 2097152);        // 8 MB
  unsigned short* hbuf = (unsigned short*)(ws + 10485760);      // 512 KB (2 bufs)
  float* hfin = (float*)(ws + 11010048);                        // 512 KB
  int* xT = (int*)(ws + 11538432);                              // 256 KB
  unsigned* pub = (unsigned*)(ws + 11800576);                   // 32 KB flags

  hipMemsetAsync(pub, 0, 32768, stream);
  hipFuncSetAttribute(reinterpret_cast<const void*>(lstm_scan),
                      hipFuncAttributeMaxDynamicSharedMemorySize, SMEM_TOTAL);

  tokproj_kernel<<<dim3(V_, 16), dim3(256), 0, stream>>>(
      emb, Wgx, Wix, Wfx, Wox, bg, bi, bf_, bo, tokproj);
  wht_kernel<<<dim3(4096), dim3(256), 0, stream>>>(Wgh, Wih, Wfh, Woh, WhT);
  xpose_kernel<<<dim3(256), dim3(256), 0, stream>>>(x, xT);
  lstm_scan<<<dim3(256), dim3(512), SMEM_TOTAL, stream>>>(
      xT, tokproj, WhT, hbuf, hfin, pub);
  classify_kernel<<<dim3(128), dim3(256), 0, stream>>>(hfin, Wph, bp, out);
}

// Round 11
// 1830.720 us; speedup vs baseline: 10.6354x; 1.0061x over previous
//
#include <hip/hip_runtime.h>

#define H_ 1024
#define B_ 128
#define S_ 512
#define V_ 128
#define E_ 256

// LDS layout (bytes)
#define ASH_OFF 0            // 32768  A fragments, XOR-swizzled
#define ZSH_OFF 32768        // 33792  [4 kg][16 row][132]
#define TSH_OFF 66560        // 67584  [128 v][132]
#define HSH_OFF 134144       // 1024   packed h slice (ushort[512])
#define XSH_OFF 135168       // 64     tokens
#define SMEM_TOTAL 135232

#define HXBUF 131072         // ushorts per hX buffer (256 blocks * 512)

typedef __bf16 bf16x8 __attribute__((ext_vector_type(8)));
typedef float f32x4 __attribute__((ext_vector_type(4)));

// Coherent (device-scope, L1/L2-bypass) 16-B load; ~1 lane-request/cyc at the
// CU (validated r7->r8->r9: step time tracks per-CU request count).
__device__ __forceinline__ uint4 cload16(const unsigned short* p) {
  uint4 r;
  asm volatile("global_load_dwordx4 %0, %1, off sc0 sc1"
               : "=v"(r) : "v"(p) : "memory");
  return r;
}
// Coherent 8-B store via compiler atomics (asm can't take wide inputs).
__device__ __forceinline__ void cstore8(unsigned short* p, unsigned long long v) {
  __hip_atomic_store((unsigned long long*)p, v, __ATOMIC_RELAXED,
                     __HIP_MEMORY_SCOPE_AGENT);
}

__device__ __forceinline__ unsigned short f2bf(float f) {
  unsigned u = __float_as_uint(f);
  u += 0x7fffu + ((u >> 16) & 1u);   // round-to-nearest-even
  return (unsigned short)(u >> 16);
}
__device__ __forceinline__ float sigf(float x) { return 1.0f / (1.0f + __expf(-x)); }
__device__ __forceinline__ float tanhfast(float x) { return 1.0f - 2.0f / (1.0f + __expf(2.0f * x)); }

// ---- tokproj[v][c] = emb[v]@Wx + b ; c = gate*1024 + j (natural layout) ----
__global__ void __launch_bounds__(256)
tokproj_kernel(const float* __restrict__ emb,
               const float* __restrict__ Wgx, const float* __restrict__ Wix,
               const float* __restrict__ Wfx, const float* __restrict__ Wox,
               const float* __restrict__ bg, const float* __restrict__ bi,
               const float* __restrict__ bf_, const float* __restrict__ bo,
               float* __restrict__ tokproj) {
  __shared__ float esh[E_];
  const int v = blockIdx.x;
  const int c = blockIdx.y * 256 + threadIdx.x;
  const int gate = c >> 10;
  const int j = c & 1023;
  const float* W = (gate == 0) ? Wgx : (gate == 1) ? Wix : (gate == 2) ? Wfx : Wox;
  const float* bias = (gate == 0) ? bg : (gate == 1) ? bi : (gate == 2) ? bf_ : bo;
  esh[threadIdx.x] = emb[v * E_ + threadIdx.x];
  __syncthreads();
  float acc = bias[j];
#pragma unroll 4
  for (int e = 0; e < E_; ++e) acc += esh[e] * W[e * H_ + j];
  tokproj[v * 4096 + c] = acc;
}

// ---- WhT[c][k] = bf16(Wh_gate[k][j]) ; c = gate*1024 + j ----
__global__ void __launch_bounds__(256)
wht_kernel(const float* __restrict__ Wgh, const float* __restrict__ Wih,
           const float* __restrict__ Wfh, const float* __restrict__ Woh,
           unsigned short* __restrict__ WhT) {
  const int c = blockIdx.x;
  const int gate = c >> 10;
  const int j = c & 1023;
  const float* W = (gate == 0) ? Wgh : (gate == 1) ? Wih : (gate == 2) ? Wfh : Woh;
  for (int k = threadIdx.x; k < H_; k += 256)
    WhT[c * H_ + k] = f2bf(W[k * H_ + j]);
}

// ---- xT[s][b] = x[b][s] ----
__global__ void __launch_bounds__(256)
xpose_kernel(const int* __restrict__ x, int* __restrict__ xT) {
  const int id = blockIdx.x * 256 + threadIdx.x;  // 65536
  const int s = id >> 7, b = id & 127;
  xT[s * 128 + b] = x[b * S_ + s];
}

// ---- persistent scan: 256 blocks x 512 thr (1 per CU) ----
// bid: rg = bid>>5 owns batch rows [rg*16,+16); cg = bid&31 owns hidden units
// [cg*32,+32). Exchange is producer-major: hX[buf][bid][row 0..16][col 0..32]
// bf16 (1 KB slice). Consumer thread tid is bound to producer p = tid>>4 of
// its own rg: polls pub[rg*32+p] only, then immediately loads 4 coalesced
// 16-B chunks of that slice. Slice chunk ci -> row ci>>2, k-chunk p*4+(ci&3).
__global__ void __launch_bounds__(512, 1)
lstm_scan(const int* __restrict__ xT, const float* __restrict__ tokproj,
          const unsigned short* __restrict__ WhT,
          unsigned short* __restrict__ hX, float* __restrict__ hfin,
          unsigned* __restrict__ pub) {
  extern __shared__ char smem[];
  char* AshB = smem + ASH_OFF;
  float* Zsh = (float*)(smem + ZSH_OFF);
  float* tsh = (float*)(smem + TSH_OFF);
  unsigned short* hsh = (unsigned short*)(smem + HSH_OFF);
  int* xsh = (int*)(smem + XSH_OFF);

  const int bid = blockIdx.x;
  const int rg = bid >> 5;
  const int cg = bid & 31;
  const int tid = threadIdx.x;
  const int w = tid >> 6;
  const int kg = w >> 1;          // k-group 0..3 (256 k each)
  const int ch = w & 1;           // col-half 0..1 (64 gate-cols each)
  const int lane = tid & 63;
  const int l15 = lane & 15;
  const int lq = lane >> 4;

  // ---- one-time: tokproj slice -> LDS (block-local col j = gate*32+hu) ----
  for (int it = tid; it < 16384; it += 512) {
    const int v = it >> 7, j = it & 127;
    tsh[v * 132 + j] = tokproj[v * 4096 + (j >> 5) * 1024 + cg * 32 + (j & 31)];
  }
  // ---- one-time: B fragments -> registers ----
  uint4 breg[32];
#pragma unroll
  for (int kc = 0; kc < 8; ++kc) {
#pragma unroll
    for (int t = 0; t < 4; ++t) {
      const int j = ch * 64 + t * 16 + l15;
      const int c = ((j >> 5) << 10) + cg * 32 + (j & 31);
      breg[kc * 4 + t] =
          *(const uint4*)(WhT + c * 1024 + (kg * 8 + kc) * 32 + lq * 8);
    }
  }

  const int row_own = tid >> 5;      // 0..15
  const int hu = tid & 31;           // 0..31
  const int brow = rg * 16 + row_own;
  const int colg = cg * 32 + hu;

  // consumer binding: producer p (within rg), chunk sub-index t
  const int p = tid >> 4;            // 0..31
  const int t = tid & 15;            // 0..15
  const unsigned* myflag = pub + (rg * 32 + p) * 32;
  const unsigned short* srcbase = hX + (rg * 32 + p) * 512;  // + buf*HXBUF

  float creg = 0.f;
  // zero own h^0 slice (buffer 0) with packed coherent stores
  if (tid < 128) cstore8(hX + bid * 512 + tid * 4, 0ull);
  asm volatile("s_waitcnt vmcnt(0)" ::: "memory");
  __syncthreads();
  if (tid == 0)
    __hip_atomic_store(pub + bid * 32, 1u, __ATOMIC_RELAXED, __HIP_MEMORY_SCOPE_AGENT);

  for (int s = 0; s < S_; ++s) {
    // ---- A: per-producer wait + coalesced slice load (overlapped) ----
    int xv = 0;
    if (tid < 16) xv = xT[s * 128 + rg * 16 + tid];
    {
      const unsigned tgt = (unsigned)(s + 1);
      while (__hip_atomic_load(myflag, __ATOMIC_RELAXED, __HIP_MEMORY_SCOPE_AGENT) < tgt)
        __builtin_amdgcn_s_sleep(1);
    }
    const unsigned short* src = srcbase + (s & 1) * HXBUF;
    uint4 av[4];
#pragma unroll
    for (int o = 0; o < 4; ++o)
      av[o] = cload16(src + (o * 16 + t) * 8);   // 16 lanes x 16 B contiguous
    asm volatile("s_waitcnt vmcnt(0)" ::: "memory");
    __builtin_amdgcn_sched_barrier(0);
#pragma unroll
    for (int o = 0; o < 4; ++o) {
      asm volatile("" : "+v"(av[o].x), "+v"(av[o].y), "+v"(av[o].z), "+v"(av[o].w));
    }

    __syncthreads();   // B: prior step fully done (AshB/hsh safe to overwrite)

    if (tid < 16) xsh[tid] = xv;
    // stage to LDS: chunk ci = o*16+t -> row r = ci>>2, k-chunk f = p*4+(ci&3)
#pragma unroll
    for (int o = 0; o < 4; ++o) {
      const int ci = o * 16 + t;
      const int f = p * 4 + (ci & 3);
      const int r = ci >> 2;
      *(uint4*)(AshB + f * 256 + ((r ^ (f & 15)) << 4)) = av[o];
    }
    __syncthreads();   // D

    // ---- MFMA: wave covers k [kg*256,+256) x cols [ch*64,+64) ----
    f32x4 acc0 = {0.f, 0.f, 0.f, 0.f}, acc1 = {0.f, 0.f, 0.f, 0.f};
    f32x4 acc2 = {0.f, 0.f, 0.f, 0.f}, acc3 = {0.f, 0.f, 0.f, 0.f};
#pragma unroll
    for (int kc = 0; kc < 8; ++kc) {
      const int f = (kg * 8 + kc) * 4 + lq;
      bf16x8 a = *(const bf16x8*)(AshB + f * 256 + ((l15 ^ (f & 15)) << 4));
      acc0 = __builtin_amdgcn_mfma_f32_16x16x32_bf16(a, __builtin_bit_cast(bf16x8, breg[kc * 4 + 0]), acc0, 0, 0, 0);
      acc1 = __builtin_amdgcn_mfma_f32_16x16x32_bf16(a, __builtin_bit_cast(bf16x8, breg[kc * 4 + 1]), acc1, 0, 0, 0);
      acc2 = __builtin_amdgcn_mfma_f32_16x16x32_bf16(a, __builtin_bit_cast(bf16x8, breg[kc * 4 + 2]), acc2, 0, 0, 0);
      acc3 = __builtin_amdgcn_mfma_f32_16x16x32_bf16(a, __builtin_bit_cast(bf16x8, breg[kc * 4 + 3]), acc3, 0, 0, 0);
    }
#pragma unroll
    for (int r_ = 0; r_ < 4; ++r_) {
      float* zr = Zsh + (kg * 16 + lq * 4 + r_) * 132 + ch * 64 + l15;
      zr[0] = acc0[r_]; zr[16] = acc1[r_]; zr[32] = acc2[r_]; zr[48] = acc3[r_];
    }
    __syncthreads();   // F

    // ---- gate pass: thread owns (row_own, hu) ----
    {
      const int xb = xsh[row_own];
      const float* tp = tsh + xb * 132;
      float z[4];
#pragma unroll
      for (int gate = 0; gate < 4; ++gate) {
        float zz = tp[gate * 32 + hu];
#pragma unroll
        for (int kgg = 0; kgg < 4; ++kgg)
          zz += Zsh[(kgg * 16 + row_own) * 132 + gate * 32 + hu];
        z[gate] = zz;
      }
      const float gv = tanhfast(z[0]);
      const float iv = sigf(z[1]);
      const float fv = sigf(z[2]);
      const float ov = sigf(z[3]);
      creg = gv * iv + creg * fv;
      const float hv = tanhfast(creg) * ov;
      hsh[row_own * 32 + hu] = f2bf(hv);
      if (s == S_ - 1) hfin[brow * H_ + colg] = hv;
    }
    __syncthreads();   // H

    // ---- packed publish: wave 0 stores the 1 KB slice + drains + flags ----
    // (vmcnt is wave-level, so wave 0's drain covers all its lanes' stores)
    if (tid < 64) {
      const unsigned long long* hp = (const unsigned long long*)hsh;
      unsigned short* dst = hX + ((s + 1) & 1) * HXBUF + bid * 512 + tid * 8;
      cstore8(dst, hp[tid * 2]);
      cstore8(dst + 4, hp[tid * 2 + 1]);
      asm volatile("s_waitcnt vmcnt(0)" ::: "memory");
      if (tid == 0)
        __hip_atomic_store(pub + bid * 32, (unsigned)(s + 2),
                           __ATOMIC_RELAXED, __HIP_MEMORY_SCOPE_AGENT);
    }
    // no barrier here: next-step polls/loads proceed; barrier B protects LDS
  }
}

// ---- p = hfin @ W_ph + b_p ; out = log_softmax(p) ----
__global__ void __launch_bounds__(256)
classify_kernel(const float* __restrict__ hfin, const float* __restrict__ Wph,
                const float* __restrict__ bp, float* __restrict__ out) {
  __shared__ float red[256 * 10];
  const int b = blockIdx.x, tid = threadIdx.x;
  float acc[10];
#pragma unroll
  for (int c = 0; c < 10; ++c) acc[c] = 0.f;
  for (int k = tid; k < H_; k += 256) {
    const float hv = hfin[b * H_ + k];
    const float* w = Wph + k * 10;
#pragma unroll
    for (int c = 0; c < 10; ++c) acc[c] += hv * w[c];
  }
#pragma unroll
  for (int c = 0; c < 10; ++c) red[tid * 10 + c] = acc[c];
  __syncthreads();
  for (int off = 128; off >= 1; off >>= 1) {
    if (tid < off) {
#pragma unroll
      for (int c = 0; c < 10; ++c) red[tid * 10 + c] += red[(tid + off) * 10 + c];
    }
    __syncthreads();
  }
  if (tid == 0) {
    float p[10];
    float m = -1e30f;
#pragma unroll
    for (int c = 0; c < 10; ++c) { p[c] = red[c] + bp[c]; m = fmaxf(m, p[c]); }
    float ssum = 0.f;
#pragma unroll
    for (int c = 0; c < 10; ++c) ssum += __expf(p[c] - m);
    const float lse = m + __logf(ssum);
#pragma unroll
    for (int c = 0; c < 10; ++c) out[b * 10 + c] = p[c] - lse;
  }
}

extern "C" void kernel_launch(void* const* d_in, const int* in_sizes, int n_in,
                              void* d_out, int out_size, void* d_ws, size_t ws_size,
                              hipStream_t stream) {
  (void)in_sizes; (void)n_in; (void)out_size; (void)ws_size;
  const int* x = (const int*)d_in[0];
  const float* emb = (const float*)d_in[1];
  const float* Wgx = (const float*)d_in[2];
  const float* Wgh = (const float*)d_in[3];
  const float* bg = (const float*)d_in[4];
  const float* Wix = (const float*)d_in[5];
  const float* Wih = (const float*)d_in[6];
  const float* bi = (const float*)d_in[7];
  const float* Wfx = (const float*)d_in[8];
  const float* Wfh = (const float*)d_in[9];
  const float* bf_ = (const float*)d_in[10];
  const float* Wox = (const float*)d_in[11];
  const float* Woh = (const float*)d_in[12];
  const float* bo = (const float*)d_in[13];
  const float* Wph = (const float*)d_in[14];
  const float* bp = (const float*)d_in[15];
  float* out = (float*)d_out;

  char* ws = (char*)d_ws;
  float* tokproj = (float*)ws;                                  // 2 MB
  unsigned short* WhT = (unsigned short*)(ws + 2097152);        // 8 MB
  unsigned short* hX = (unsigned short*)(ws + 10485760);        // 512 KB (2 bufs)
  float* hfin = (float*)(ws + 11010048);                        // 512 KB
  int* xT = (int*)(ws + 11538432);                              // 256 KB
  unsigned* pub = (unsigned*)(ws + 11800576);                   // 32 KB flags

  (void)hipMemsetAsync(pub, 0, 32768, stream);
  (void)hipFuncSetAttribute(reinterpret_cast<const void*>(lstm_scan),
                            hipFuncAttributeMaxDynamicSharedMemorySize, SMEM_TOTAL);

  tokproj_kernel<<<dim3(V_, 16), dim3(256), 0, stream>>>(
      emb, Wgx, Wix, Wfx, Wox, bg, bi, bf_, bo, tokproj);
  wht_kernel<<<dim3(4096), dim3(256), 0, stream>>>(Wgh, Wih, Wfh, Woh, WhT);
  xpose_kernel<<<dim3(256), dim3(256), 0, stream>>>(x, xT);
  lstm_scan<<<dim3(256), dim3(512), SMEM_TOTAL, stream>>>(
      xT, tokproj, WhT, hX, hfin, pub);
  classify_kernel<<<dim3(128), dim3(256), 0, stream>>>(hfin, Wph, bp, out);
}